// Round 12
// baseline (399.900 us; speedup 1.0000x reference)
//
#include <hip/hip_runtime.h>
#include <math.h>

// Problem constants (B=1 throughout)
#define S_   4096
#define D_   2048
#define M_   4
#define NC_  1024
#define TOPK_ 512
#define NH_  16
#define C_   64
#define DC_  512
#define NG_  4
#define DG_  512
#define CI_  64
#define NHI_ 4
#define ROPE_ 32
#define EPS_ 1e-6f

typedef __attribute__((ext_vector_type(8))) short short8;
typedef __attribute__((ext_vector_type(4))) short short4v;
typedef __attribute__((ext_vector_type(4))) float floatx4;

__device__ inline unsigned short f2bf(float f) {
  unsigned u = __float_as_uint(f);
  u += 0x7fff + ((u >> 16) & 1);   // round-to-nearest-even
  return (unsigned short)(u >> 16);
}
__device__ inline float bf2f(unsigned short h) {
  return __uint_as_float(((unsigned)h) << 16);
}

#define GLD16(src, dst) __builtin_amdgcn_global_load_lds( \
    (const __attribute__((address_space(1))) unsigned int*)(src), \
    (__attribute__((address_space(3))) unsigned int*)(dst), 16, 0, 0)

// Bijective XCD-chunk swizzle (T1): blocks sharing an A-panel (consecutive
// flat ids, x-fastest) land on the SAME XCD L2. Requires nwg % 8 == 0.
__device__ inline void xcd_remap(int& bx, int& by, int& bz) {
  int nx = gridDim.x, ny = gridDim.y;
  int flat = blockIdx.x + nx * (blockIdx.y + ny * blockIdx.z);
  int nwg = nx * ny * (int)gridDim.z;
  int swz = (flat & 7) * (nwg >> 3) + (flat >> 3);
  bx = swz % nx;
  int t = swz / nx;
  by = t % ny;
  bz = t / ny;
}

// ---------------------------------------------------------------------------
// bf16 MFMA GEMM, 64x128 tile (4 waves x 32x64). C = A @ Bt^T, grid.z strides.
// Double-buffered LDS, BK=64, ONE barrier/K-tile. XCD-swizzled.
// ---------------------------------------------------------------------------
__global__ __launch_bounds__(256) void gemm_bf16_64(
    const unsigned short* __restrict__ A, const unsigned short* __restrict__ Bt,
    float* __restrict__ Cf, unsigned short* __restrict__ Cb,
    int K, int lda, int ldb, int ldc,
    long long Az, long long Bz, long long Cz) {
  int bx, by, zz;
  xcd_remap(bx, by, zz);
  A += (size_t)zz * Az;
  Bt += (size_t)zz * Bz;
  if (Cf) Cf += (size_t)zz * Cz;
  if (Cb) Cb += (size_t)zz * Cz;
  __shared__ unsigned short As[2 * 2 * 64 * 32];    // 16 KB
  __shared__ unsigned short Bs[2 * 2 * 128 * 32];   // 32 KB
  int tid = threadIdx.x;
  int bm = by * 64, bn = bx * 128;
  int lane = tid & 63, wid = tid >> 6;
  int wm = (wid & 1) * 32, wn = (wid >> 1) * 64;
  int qd = lane >> 4, m16 = lane & 15;

  floatx4 acc[2][4];
#pragma unroll
  for (int i = 0; i < 2; ++i)
#pragma unroll
    for (int j = 0; j < 4; ++j) acc[i][j] = (floatx4){0.f, 0.f, 0.f, 0.f};

  auto stage = [&](int buf, int kt) {
#pragma unroll
    for (int h = 0; h < 2; ++h) {
      {
        int rr = tid >> 2, ss = tid & 3;
        int gg = ss ^ ((rr >> 1) & 3);
        GLD16(A + (size_t)(bm + rr) * lda + kt + h * 32 + gg * 8,
              &As[(buf * 2 + h) * 2048 + tid * 8]);
      }
#pragma unroll
      for (int i = 0; i < 2; ++i) {
        int idx = tid + 256 * i;
        int rr = idx >> 2, ss = idx & 3;
        int gg = ss ^ ((rr >> 1) & 3);
        GLD16(Bt + (size_t)(bn + rr) * ldb + kt + h * 32 + gg * 8,
              &Bs[(buf * 2 + h) * 4096 + idx * 8]);
      }
    }
  };
  auto compute = [&](int buf) {
#pragma unroll
    for (int h = 0; h < 2; ++h) {
      const unsigned short* Ab = &As[(buf * 2 + h) * 2048];
      const unsigned short* Bb = &Bs[(buf * 2 + h) * 4096];
      short8 af[2], bfr[4];
#pragma unroll
      for (int mi = 0; mi < 2; ++mi) {
        int r = wm + mi * 16 + m16;
        int slot = qd ^ ((r >> 1) & 3);
        af[mi] = *(const short8*)&Ab[r * 32 + slot * 8];
      }
#pragma unroll
      for (int ni = 0; ni < 4; ++ni) {
        int r = wn + ni * 16 + m16;
        int slot = qd ^ ((r >> 1) & 3);
        bfr[ni] = *(const short8*)&Bb[r * 32 + slot * 8];
      }
#pragma unroll
      for (int mi = 0; mi < 2; ++mi)
#pragma unroll
        for (int ni = 0; ni < 4; ++ni)
          acc[mi][ni] = __builtin_amdgcn_mfma_f32_16x16x32_bf16(af[mi], bfr[ni], acc[mi][ni], 0, 0, 0);
    }
  };

  stage(0, 0);
  __syncthreads();
  int cur = 0;
  for (int kt = 64; kt < K; kt += 64) {
    stage(cur ^ 1, kt);
    compute(cur);
    __syncthreads();
    cur ^= 1;
  }
  compute(cur);

#pragma unroll
  for (int mi = 0; mi < 2; ++mi)
#pragma unroll
    for (int ni = 0; ni < 4; ++ni) {
      int col = bn + wn + ni * 16 + m16;
#pragma unroll
      for (int rg = 0; rg < 4; ++rg) {
        int row = bm + wm + mi * 16 + qd * 4 + rg;
        if (Cb)
          Cb[(size_t)row * ldc + col] = f2bf(acc[mi][ni][rg]);
        else
          Cf[(size_t)row * ldc + col] = acc[mi][ni][rg];
      }
    }
}

// ---------------------------------------------------------------------------
// bf16 MFMA GEMM, 128x128 tile (4 waves x 64x64). C = A @ Bt^T, grid.z strides.
// Double-buffered LDS, BK=64, ONE barrier/K-tile. XCD-swizzled.
// ---------------------------------------------------------------------------
__global__ __launch_bounds__(256) void gemm_bf16_128(
    const unsigned short* __restrict__ A, const unsigned short* __restrict__ Bt,
    float* __restrict__ Cf, unsigned short* __restrict__ Cb,
    int K, int lda, int ldb, int ldc,
    long long Az, long long Bz, long long Cz) {
  int bx, by, zz;
  xcd_remap(bx, by, zz);
  A += (size_t)zz * Az;
  Bt += (size_t)zz * Bz;
  if (Cf) Cf += (size_t)zz * Cz;
  if (Cb) Cb += (size_t)zz * Cz;
  __shared__ unsigned short As[2 * 2 * 128 * 32];   // 32 KB
  __shared__ unsigned short Bs[2 * 2 * 128 * 32];   // 32 KB
  int tid = threadIdx.x;
  int bm = by * 128, bn = bx * 128;
  int lane = tid & 63, wid = tid >> 6;
  int wm = (wid & 1) * 64, wn = (wid >> 1) * 64;
  int qd = lane >> 4, m16 = lane & 15;

  floatx4 acc[4][4];
#pragma unroll
  for (int i = 0; i < 4; ++i)
#pragma unroll
    for (int j = 0; j < 4; ++j) acc[i][j] = (floatx4){0.f, 0.f, 0.f, 0.f};

  auto stage = [&](int buf, int kt) {
#pragma unroll
    for (int h = 0; h < 2; ++h) {
#pragma unroll
      for (int i = 0; i < 2; ++i) {
        int idx = tid + 256 * i;
        int rr = idx >> 2, ss = idx & 3;
        int gg = ss ^ ((rr >> 1) & 3);
        GLD16(A + (size_t)(bm + rr) * lda + kt + h * 32 + gg * 8,
              &As[(buf * 2 + h) * 4096 + idx * 8]);
        GLD16(Bt + (size_t)(bn + rr) * ldb + kt + h * 32 + gg * 8,
              &Bs[(buf * 2 + h) * 4096 + idx * 8]);
      }
    }
  };
  auto compute = [&](int buf) {
#pragma unroll
    for (int h = 0; h < 2; ++h) {
      const unsigned short* Ab = &As[(buf * 2 + h) * 4096];
      const unsigned short* Bb = &Bs[(buf * 2 + h) * 4096];
      short8 af[4], bfr[4];
#pragma unroll
      for (int mi = 0; mi < 4; ++mi) {
        int r = wm + mi * 16 + m16;
        int slot = qd ^ ((r >> 1) & 3);
        af[mi] = *(const short8*)&Ab[r * 32 + slot * 8];
      }
#pragma unroll
      for (int ni = 0; ni < 4; ++ni) {
        int r = wn + ni * 16 + m16;
        int slot = qd ^ ((r >> 1) & 3);
        bfr[ni] = *(const short8*)&Bb[r * 32 + slot * 8];
      }
#pragma unroll
      for (int mi = 0; mi < 4; ++mi)
#pragma unroll
        for (int ni = 0; ni < 4; ++ni)
          acc[mi][ni] = __builtin_amdgcn_mfma_f32_16x16x32_bf16(af[mi], bfr[ni], acc[mi][ni], 0, 0, 0);
    }
  };

  stage(0, 0);
  __syncthreads();
  int cur = 0;
  for (int kt = 64; kt < K; kt += 64) {
    stage(cur ^ 1, kt);
    compute(cur);
    __syncthreads();
    cur ^= 1;
  }
  compute(cur);

#pragma unroll
  for (int mi = 0; mi < 4; ++mi)
#pragma unroll
    for (int ni = 0; ni < 4; ++ni) {
      int col = bn + wn + ni * 16 + m16;
#pragma unroll
      for (int rg = 0; rg < 4; ++rg) {
        int row = bm + wm + mi * 16 + qd * 4 + rg;
        if (Cb)
          Cb[(size_t)row * ldc + col] = f2bf(acc[mi][ni][rg]);
        else
          Cf[(size_t)row * ldc + col] = acc[mi][ni][rg];
      }
    }
}

// ---------------------------------------------------------------------------
// Split-bf16 MFMA GEMM, 64x128 tile (fp32-accurate, 3 MFMA terms).
// ---------------------------------------------------------------------------
__global__ __launch_bounds__(256) void gemm_bf16_split_64(
    const unsigned short* __restrict__ Ah, const unsigned short* __restrict__ Al,
    const unsigned short* __restrict__ Bh, const unsigned short* __restrict__ Bl,
    float* __restrict__ Cf, int K, int lda, int ldb, int ldc,
    long long Az, long long Bz, long long Cz) {
  int bx, by, zz;
  xcd_remap(bx, by, zz);
  Ah += (size_t)zz * Az; Al += (size_t)zz * Az;
  Bh += (size_t)zz * Bz; Bl += (size_t)zz * Bz;
  Cf += (size_t)zz * Cz;
  __shared__ unsigned short Ash[64 * 32];
  __shared__ unsigned short Asl[64 * 32];
  __shared__ unsigned short Bsh[128 * 32];
  __shared__ unsigned short Bsl[128 * 32];
  int tid = threadIdx.x;
  int bm = by * 64, bn = bx * 128;
  int lane = tid & 63, wid = tid >> 6;
  int wm = (wid & 1) * 32, wn = (wid >> 1) * 64;
  int qd = lane >> 4, m16 = lane & 15;

  floatx4 acc[2][4];
#pragma unroll
  for (int i = 0; i < 2; ++i)
#pragma unroll
    for (int j = 0; j < 4; ++j) acc[i][j] = (floatx4){0.f, 0.f, 0.f, 0.f};

  for (int k0 = 0; k0 < K; k0 += 32) {
    {
      int r = tid >> 2, sl = tid & 3;
      int g = sl ^ ((r >> 1) & 3);
      size_t aoff = (size_t)(bm + r) * lda + k0 + g * 8;
      GLD16(Ah + aoff, &Ash[tid * 8]);
      GLD16(Al + aoff, &Asl[tid * 8]);
    }
#pragma unroll
    for (int i = 0; i < 2; ++i) {
      int idx = tid + 256 * i;
      int r = idx >> 2, sl = idx & 3;
      int g = sl ^ ((r >> 1) & 3);
      size_t boff = (size_t)(bn + r) * ldb + k0 + g * 8;
      GLD16(Bh + boff, &Bsh[idx * 8]);
      GLD16(Bl + boff, &Bsl[idx * 8]);
    }
    __syncthreads();
    short8 afh[2], afl[2], bfh[4], bfl[4];
#pragma unroll
    for (int mi = 0; mi < 2; ++mi) {
      int r = wm + mi * 16 + m16;
      int slot = qd ^ ((r >> 1) & 3);
      afh[mi] = *(const short8*)&Ash[r * 32 + slot * 8];
      afl[mi] = *(const short8*)&Asl[r * 32 + slot * 8];
    }
#pragma unroll
    for (int ni = 0; ni < 4; ++ni) {
      int r = wn + ni * 16 + m16;
      int slot = qd ^ ((r >> 1) & 3);
      bfh[ni] = *(const short8*)&Bsh[r * 32 + slot * 8];
      bfl[ni] = *(const short8*)&Bsl[r * 32 + slot * 8];
    }
#pragma unroll
    for (int mi = 0; mi < 2; ++mi)
#pragma unroll
      for (int ni = 0; ni < 4; ++ni) {
        acc[mi][ni] = __builtin_amdgcn_mfma_f32_16x16x32_bf16(afh[mi], bfh[ni], acc[mi][ni], 0, 0, 0);
        acc[mi][ni] = __builtin_amdgcn_mfma_f32_16x16x32_bf16(afh[mi], bfl[ni], acc[mi][ni], 0, 0, 0);
        acc[mi][ni] = __builtin_amdgcn_mfma_f32_16x16x32_bf16(afl[mi], bfh[ni], acc[mi][ni], 0, 0, 0);
      }
    __syncthreads();
  }
#pragma unroll
  for (int mi = 0; mi < 2; ++mi)
#pragma unroll
    for (int ni = 0; ni < 4; ++ni) {
      int col = bn + wn + ni * 16 + m16;
#pragma unroll
      for (int rg = 0; rg < 4; ++rg) {
        int row = bm + wm + mi * 16 + qd * 4 + rg;
        Cf[(size_t)row * ldc + col] = acc[mi][ni][rg];
      }
    }
}

// ---------------------------------------------------------------------------
// Split-bf16 MFMA GEMM, 128x128 tile (fp32-accurate, 3 MFMA terms).
// Double-buffered LDS, BK=32, ONE barrier/K-tile.
// ---------------------------------------------------------------------------
__global__ __launch_bounds__(256) void gemm_bf16_split_128(
    const unsigned short* __restrict__ Ah, const unsigned short* __restrict__ Al,
    const unsigned short* __restrict__ Bh, const unsigned short* __restrict__ Bl,
    float* __restrict__ Cf, int K, int lda, int ldb, int ldc,
    long long Az, long long Bz, long long Cz) {
  int bx, by, zz;
  xcd_remap(bx, by, zz);
  Ah += (size_t)zz * Az; Al += (size_t)zz * Az;
  Bh += (size_t)zz * Bz; Bl += (size_t)zz * Bz;
  Cf += (size_t)zz * Cz;
  __shared__ unsigned short Ash[2 * 128 * 32];   // 16 KB each
  __shared__ unsigned short Asl[2 * 128 * 32];
  __shared__ unsigned short Bsh[2 * 128 * 32];
  __shared__ unsigned short Bsl[2 * 128 * 32];
  int tid = threadIdx.x;
  int bm = by * 128, bn = bx * 128;
  int lane = tid & 63, wid = tid >> 6;
  int wm = (wid & 1) * 64, wn = (wid >> 1) * 64;
  int qd = lane >> 4, m16 = lane & 15;

  floatx4 acc[4][4];
#pragma unroll
  for (int i = 0; i < 4; ++i)
#pragma unroll
    for (int j = 0; j < 4; ++j) acc[i][j] = (floatx4){0.f, 0.f, 0.f, 0.f};

  auto stage = [&](int buf, int kt) {
#pragma unroll
    for (int i = 0; i < 2; ++i) {
      int idx = tid + 256 * i;
      int rr = idx >> 2, ss = idx & 3;
      int gg = ss ^ ((rr >> 1) & 3);
      size_t aoff = (size_t)(bm + rr) * lda + kt + gg * 8;
      size_t boff = (size_t)(bn + rr) * ldb + kt + gg * 8;
      GLD16(Ah + aoff, &Ash[buf * 4096 + idx * 8]);
      GLD16(Al + aoff, &Asl[buf * 4096 + idx * 8]);
      GLD16(Bh + boff, &Bsh[buf * 4096 + idx * 8]);
      GLD16(Bl + boff, &Bsl[buf * 4096 + idx * 8]);
    }
  };
  auto compute = [&](int buf) {
    const unsigned short* Ahb = &Ash[buf * 4096];
    const unsigned short* Alb = &Asl[buf * 4096];
    const unsigned short* Bhb = &Bsh[buf * 4096];
    const unsigned short* Blb = &Bsl[buf * 4096];
    short8 afh[4], afl[4], bfh[4], bfl[4];
#pragma unroll
    for (int mi = 0; mi < 4; ++mi) {
      int r = wm + mi * 16 + m16;
      int slot = qd ^ ((r >> 1) & 3);
      afh[mi] = *(const short8*)&Ahb[r * 32 + slot * 8];
      afl[mi] = *(const short8*)&Alb[r * 32 + slot * 8];
    }
#pragma unroll
    for (int ni = 0; ni < 4; ++ni) {
      int r = wn + ni * 16 + m16;
      int slot = qd ^ ((r >> 1) & 3);
      bfh[ni] = *(const short8*)&Bhb[r * 32 + slot * 8];
      bfl[ni] = *(const short8*)&Blb[r * 32 + slot * 8];
    }
#pragma unroll
    for (int mi = 0; mi < 4; ++mi)
#pragma unroll
      for (int ni = 0; ni < 4; ++ni) {
        acc[mi][ni] = __builtin_amdgcn_mfma_f32_16x16x32_bf16(afh[mi], bfh[ni], acc[mi][ni], 0, 0, 0);
        acc[mi][ni] = __builtin_amdgcn_mfma_f32_16x16x32_bf16(afh[mi], bfl[ni], acc[mi][ni], 0, 0, 0);
        acc[mi][ni] = __builtin_amdgcn_mfma_f32_16x16x32_bf16(afl[mi], bfh[ni], acc[mi][ni], 0, 0, 0);
      }
  };

  stage(0, 0);
  __syncthreads();
  int cur = 0;
  for (int kt = 32; kt < K; kt += 32) {
    stage(cur ^ 1, kt);
    compute(cur);
    __syncthreads();
    cur ^= 1;
  }
  compute(cur);

#pragma unroll
  for (int mi = 0; mi < 4; ++mi)
#pragma unroll
    for (int ni = 0; ni < 4; ++ni) {
      int col = bn + wn + ni * 16 + m16;
#pragma unroll
      for (int rg = 0; rg < 4; ++rg) {
        int row = bm + wm + mi * 16 + qd * 4 + rg;
        Cf[(size_t)row * ldc + col] = acc[mi][ni][rg];
      }
    }
}

// reduce z fp32 slices -> (bf16 hi, bf16 lo)
__global__ void reduce_cast_split(const float* __restrict__ P, unsigned short* __restrict__ hi,
                                  unsigned short* __restrict__ lo, int n, int z) {
  int i = (blockIdx.x * 256 + threadIdx.x) * 4;
  if (i >= n) return;
  float4 a = *(const float4*)&P[i];
  for (int s = 1; s < z; ++s) {
    float4 b = *(const float4*)&P[(size_t)s * n + i];
    a.x += b.x; a.y += b.y; a.z += b.z; a.w += b.w;
  }
  ushort4 h = make_ushort4(f2bf(a.x), f2bf(a.y), f2bf(a.z), f2bf(a.w));
  ushort4 l = make_ushort4(f2bf(a.x - bf2f(h.x)), f2bf(a.y - bf2f(h.y)),
                           f2bf(a.z - bf2f(h.z)), f2bf(a.w - bf2f(h.w)));
  *(ushort4*)&hi[i] = h;
  *(ushort4*)&lo[i] = l;
}

// ---------------------------------------------------------------------------
// Indexer scores on split-bf16 MFMA (relu*hw epilogue in-register).
// ---------------------------------------------------------------------------
__global__ __launch_bounds__(256) void iscores_mfma(
    const unsigned short* __restrict__ Ah, const unsigned short* __restrict__ Al,
    const unsigned short* __restrict__ Bh, const unsigned short* __restrict__ Bl,
    const float* __restrict__ hw, float* __restrict__ isc) {
  int bm = blockIdx.y * 128, bn = blockIdx.x * 128;
  if (bn > (bm >> 2) + 30) return;
  __shared__ unsigned short Ash[128 * 32];
  __shared__ unsigned short Asl[128 * 32];
  __shared__ unsigned short Bsh[128 * 32];
  __shared__ unsigned short Bsl[128 * 32];
  int tid = threadIdx.x;
  int lane = tid & 63, wid = tid >> 6;
  int wm = (wid >> 1) * 64, wn = (wid & 1) * 64;
  int qd = lane >> 4, m16 = lane & 15;

  floatx4 acc[4][4];
#pragma unroll
  for (int i = 0; i < 4; ++i)
#pragma unroll
    for (int j = 0; j < 4; ++j) acc[i][j] = (floatx4){0.f, 0.f, 0.f, 0.f};

#pragma unroll
  for (int k0 = 0; k0 < 64; k0 += 32) {
#pragma unroll
    for (int i = 0; i < 2; ++i) {
      int idx = tid + 256 * i;
      int r = idx >> 2, s = idx & 3;
      int g = s ^ ((r >> 1) & 3);
      size_t aoff = (size_t)(bm + r) * 64 + k0 + g * 8;
      size_t boff = (size_t)(bn + r) * 64 + k0 + g * 8;
      GLD16(Ah + aoff, &Ash[idx * 8]);
      GLD16(Al + aoff, &Asl[idx * 8]);
      GLD16(Bh + boff, &Bsh[idx * 8]);
      GLD16(Bl + boff, &Bsl[idx * 8]);
    }
    __syncthreads();
    short8 afh[4], afl[4], bfh[4], bfl[4];
#pragma unroll
    for (int mi = 0; mi < 4; ++mi) {
      int r = wm + mi * 16 + m16;
      int slot = qd ^ ((r >> 1) & 3);
      afh[mi] = *(const short8*)&Ash[r * 32 + slot * 8];
      afl[mi] = *(const short8*)&Asl[r * 32 + slot * 8];
    }
#pragma unroll
    for (int ni = 0; ni < 4; ++ni) {
      int r = wn + ni * 16 + m16;
      int slot = qd ^ ((r >> 1) & 3);
      bfh[ni] = *(const short8*)&Bsh[r * 32 + slot * 8];
      bfl[ni] = *(const short8*)&Bsl[r * 32 + slot * 8];
    }
#pragma unroll
    for (int mi = 0; mi < 4; ++mi)
#pragma unroll
      for (int ni = 0; ni < 4; ++ni) {
        acc[mi][ni] = __builtin_amdgcn_mfma_f32_16x16x32_bf16(afh[mi], bfh[ni], acc[mi][ni], 0, 0, 0);
        acc[mi][ni] = __builtin_amdgcn_mfma_f32_16x16x32_bf16(afh[mi], bfl[ni], acc[mi][ni], 0, 0, 0);
        acc[mi][ni] = __builtin_amdgcn_mfma_f32_16x16x32_bf16(afl[mi], bfh[ni], acc[mi][ni], 0, 0, 0);
      }
    __syncthreads();
  }
#pragma unroll
  for (int mi = 0; mi < 4; ++mi) {
    int tok = ((bm + wm + mi * 16) >> 2) + qd;
    float4 hwv = *(const float4*)&hw[tok * 4];
#pragma unroll
    for (int ni = 0; ni < 4; ++ni) {
      floatx4 a = acc[mi][ni];
      float v = fmaxf(a[0], 0.f) * hwv.x + fmaxf(a[1], 0.f) * hwv.y +
                fmaxf(a[2], 0.f) * hwv.z + fmaxf(a[3], 0.f) * hwv.w;
      int col = bn + wn + ni * 16 + m16;
      isc[(size_t)tok * NC_ + col] = (col < tok) ? v : -__builtin_inff();
    }
  }
}

// ---------------------------------------------------------------------------
// Split-K fp32 GEMM for k_proj (N=64) + fused reduce+cast_split
// ---------------------------------------------------------------------------
#define BM 64
#define BN 64
#define BK 16
#define KSL_ 16
#define KSLICE_ 128
__global__ __launch_bounds__(256) void gemm_f32_splitk(
    const float* __restrict__ A, const float* __restrict__ B,
    float* __restrict__ P, int lda, int ldb) {
  __shared__ float As[BK][BM + 4];
  __shared__ float Bs[BK][BN + 4];
  int tid = threadIdx.x;
  int bm = blockIdx.y * BM;
  int kbase = blockIdx.x * KSLICE_;
  int tr = tid >> 4;
  int tc = tid & 15;
  float acc[4][4] = {{0.f}};
  for (int k0 = kbase; k0 < kbase + KSLICE_; k0 += BK) {
    int ac = tid & 15;
    int ar0 = tid >> 4;
#pragma unroll
    for (int i = 0; i < 4; ++i) {
      int r = ar0 + 16 * i;
      As[ac][r] = A[(size_t)(bm + r) * lda + k0 + ac];
    }
    int bc = tid & 63;
    int br0 = tid >> 6;
#pragma unroll
    for (int i = 0; i < 4; ++i) {
      int r = br0 + 4 * i;
      Bs[r][bc] = B[(size_t)(k0 + r) * ldb + bc];
    }
    __syncthreads();
#pragma unroll
    for (int kk = 0; kk < BK; ++kk) {
      float4 av = *(const float4*)&As[kk][tr * 4];
      float4 bv = *(const float4*)&Bs[kk][tc * 4];
      float a[4] = {av.x, av.y, av.z, av.w};
      float b[4] = {bv.x, bv.y, bv.z, bv.w};
#pragma unroll
      for (int i = 0; i < 4; ++i)
#pragma unroll
        for (int j = 0; j < 4; ++j) acc[i][j] += a[i] * b[j];
    }
    __syncthreads();
  }
  float* Pb = P + (size_t)blockIdx.x * (NC_ * CI_);
#pragma unroll
  for (int i = 0; i < 4; ++i) {
    float4 v = make_float4(acc[i][0], acc[i][1], acc[i][2], acc[i][3]);
    *(float4*)&Pb[(size_t)(bm + tr * 4 + i) * CI_ + tc * 4] = v;
  }
}

// fused: reduce 16 split-K slices -> (bf16 hi, bf16 lo) directly (no k_pr)
__global__ void reduce_splitk_cast(const float* __restrict__ P,
                                   unsigned short* __restrict__ hi,
                                   unsigned short* __restrict__ lo) {
  int i = blockIdx.x * 256 + threadIdx.x;
  float a = 0.f;
#pragma unroll
  for (int s = 0; s < KSL_; ++s) a += P[(size_t)s * (NC_ * CI_) + i];
  unsigned short h = f2bf(a);
  hi[i] = h;
  lo[i] = f2bf(a - bf2f(h));
}

__device__ inline float wave_sum64(float v) {
#pragma unroll
  for (int off = 32; off > 0; off >>= 1) v += __shfl_xor(v, off, 64);
  return v;
}

// Fused: x -> (hi, lo) split, hw = x @ w_w, AND k_or chunk mean.
__global__ __launch_bounds__(512) void cast_split_hw_mean(
    const float* __restrict__ x, unsigned short* __restrict__ hi,
    unsigned short* __restrict__ lo, const float* __restrict__ ww,
    float* __restrict__ hw, float* __restrict__ ko) {
  int j = blockIdx.x, tid = threadIdx.x;
  int d0 = tid * 4;
  const float* wr = ww + d0 * 4;
  float4 v[4];
  float a[4][4];
#pragma unroll
  for (int m = 0; m < 4; ++m) {
    size_t i = (size_t)(j * 4 + m) * D_ + d0;
    v[m] = *(const float4*)&x[i];
    ushort4 h = make_ushort4(f2bf(v[m].x), f2bf(v[m].y), f2bf(v[m].z), f2bf(v[m].w));
    ushort4 l = make_ushort4(f2bf(v[m].x - bf2f(h.x)), f2bf(v[m].y - bf2f(h.y)),
                             f2bf(v[m].z - bf2f(h.z)), f2bf(v[m].w - bf2f(h.w)));
    *(ushort4*)&hi[i] = h;
    *(ushort4*)&lo[i] = l;
    a[m][0] = v[m].x * wr[0] + v[m].y * wr[4] + v[m].z * wr[8]  + v[m].w * wr[12];
    a[m][1] = v[m].x * wr[1] + v[m].y * wr[5] + v[m].z * wr[9]  + v[m].w * wr[13];
    a[m][2] = v[m].x * wr[2] + v[m].y * wr[6] + v[m].z * wr[10] + v[m].w * wr[14];
    a[m][3] = v[m].x * wr[3] + v[m].y * wr[7] + v[m].z * wr[11] + v[m].w * wr[15];
  }
  float4 s4;
  s4.x = 0.25f * (v[0].x + v[1].x + v[2].x + v[3].x);
  s4.y = 0.25f * (v[0].y + v[1].y + v[2].y + v[3].y);
  s4.z = 0.25f * (v[0].z + v[1].z + v[2].z + v[3].z);
  s4.w = 0.25f * (v[0].w + v[1].w + v[2].w + v[3].w);
  *(float4*)&ko[(size_t)j * D_ + d0] = s4;
#pragma unroll
  for (int m = 0; m < 4; ++m)
#pragma unroll
    for (int h2 = 0; h2 < 4; ++h2) a[m][h2] = wave_sum64(a[m][h2]);
  __shared__ float red[8][16];
  int wid = tid >> 6, lane = tid & 63;
  if (lane == 0) {
#pragma unroll
    for (int m = 0; m < 4; ++m)
#pragma unroll
      for (int h2 = 0; h2 < 4; ++h2) red[wid][m * 4 + h2] = a[m][h2];
  }
  __syncthreads();
  if (tid < 16) {
    float acc = 0.f;
#pragma unroll
    for (int w2 = 0; w2 < 8; ++w2) acc += red[w2][tid];
    hw[(size_t)(j * 4 + (tid >> 2)) * 4 + (tid & 3)] = acc;
  }
}

// ---------------------------------------------------------------------------
// PREP megakernel: 10 preprocessing launches fused into one (block ranges).
// ---------------------------------------------------------------------------
__global__ __launch_bounds__(256) void prep_kernel(
    const float* __restrict__ w_kv_a, const float* __restrict__ w_kv_b,
    const float* __restrict__ w_z_a, const float* __restrict__ w_z_b,
    unsigned short* __restrict__ wpackT,
    const float* __restrict__ w_dq, unsigned short* __restrict__ wdqTh,
    unsigned short* __restrict__ wdqTl,
    const float* __restrict__ w_iuq, unsigned short* __restrict__ wiuqTh,
    unsigned short* __restrict__ wiuqTl,
    const float* __restrict__ w_uq, unsigned short* __restrict__ wuqT,
    const float* __restrict__ o_down, unsigned short* __restrict__ odb,
    const float* __restrict__ o_up, unsigned short* __restrict__ oupT,
    float* __restrict__ rt) {
  __shared__ float t[32][33];
  int b = blockIdx.x;
  int tid = threadIdx.x;
  int tx = tid & 31, ty = tid >> 5;
  if (b < 512) {
    int wsel = b >> 7, local = b & 127;
    int bx = local & 63, by = local >> 6;
    const float* in = (wsel == 0) ? w_kv_a : (wsel == 1) ? w_kv_b : (wsel == 2) ? w_z_a : w_z_b;
    unsigned short* outp = wpackT + wsel * 64 * 2048;
    int k0 = bx * 32, n0 = by * 32;
#pragma unroll
    for (int i = 0; i < 4; ++i)
      t[ty * 4 + i][tx] = in[(size_t)(k0 + ty * 4 + i) * 64 + n0 + tx];
    __syncthreads();
#pragma unroll
    for (int i = 0; i < 4; ++i)
      outp[(size_t)(n0 + ty * 4 + i) * 2048 + k0 + tx] = f2bf(t[tx][ty * 4 + i]);
  } else if (b < 1536) {
    int local = b - 512;
    int bx = local & 63, by = local >> 6;
    int k0 = bx * 32, n0 = by * 32;
#pragma unroll
    for (int i = 0; i < 4; ++i)
      t[ty * 4 + i][tx] = w_dq[(size_t)(k0 + ty * 4 + i) * 512 + n0 + tx];
    __syncthreads();
#pragma unroll
    for (int i = 0; i < 4; ++i) {
      float v = t[tx][ty * 4 + i];
      unsigned short h = f2bf(v);
      wdqTh[(size_t)(n0 + ty * 4 + i) * 2048 + k0 + tx] = h;
      wdqTl[(size_t)(n0 + ty * 4 + i) * 2048 + k0 + tx] = f2bf(v - bf2f(h));
    }
  } else if (b < 1664) {
    int local = b - 1536;
    int bx = local & 15, by = local >> 4;
    int k0 = bx * 32, n0 = by * 32;
#pragma unroll
    for (int i = 0; i < 4; ++i)
      t[ty * 4 + i][tx] = w_iuq[(size_t)(k0 + ty * 4 + i) * 256 + n0 + tx];
    __syncthreads();
#pragma unroll
    for (int i = 0; i < 4; ++i) {
      float v = t[tx][ty * 4 + i];
      unsigned short h = f2bf(v);
      wiuqTh[(size_t)(n0 + ty * 4 + i) * 512 + k0 + tx] = h;
      wiuqTl[(size_t)(n0 + ty * 4 + i) * 512 + k0 + tx] = f2bf(v - bf2f(h));
    }
  } else if (b < 2176) {
    int local = b - 1664;
    int bx = local & 15, by = local >> 4;
    int k0 = bx * 32, n0 = by * 32;
#pragma unroll
    for (int i = 0; i < 4; ++i)
      t[ty * 4 + i][tx] = w_uq[(size_t)(k0 + ty * 4 + i) * 1024 + n0 + tx];
    __syncthreads();
#pragma unroll
    for (int i = 0; i < 4; ++i)
      wuqT[(size_t)(n0 + ty * 4 + i) * 512 + k0 + tx] = f2bf(t[tx][ty * 4 + i]);
  } else if (b < 2688) {
    int i = ((b - 2176) * 256 + tid) * 4;
    float4 v = *(const float4*)&o_down[i];
    ushort4 o = make_ushort4(f2bf(v.x), f2bf(v.y), f2bf(v.z), f2bf(v.w));
    *(ushort4*)&odb[i] = o;
  } else if (b < 6784) {
    int local = b - 2688;
    int bx = local & 63, by = local >> 6;
    int k0 = bx * 32, n0 = by * 32;
#pragma unroll
    for (int i = 0; i < 4; ++i)
      t[ty * 4 + i][tx] = o_up[(size_t)(k0 + ty * 4 + i) * 2048 + n0 + tx];
    __syncthreads();
#pragma unroll
    for (int i = 0; i < 4; ++i)
      oupT[(size_t)(n0 + ty * 4 + i) * 2048 + k0 + tx] = f2bf(t[tx][ty * 4 + i]);
  } else {
    int i = (b - 6784) * 256 + tid;
    int s = i >> 4, p = i & 15;
    float inv = powf(10000.f, -(2.f * (float)p) / (float)ROPE_);
    float ang = (float)s * inv;
    rt[i * 2] = cosf(ang);
    rt[i * 2 + 1] = sinf(ang);
  }
}

// ---------------------------------------------------------------------------
// Fused gating softmax + LayerNorm -> kcb/kcbT, reading the c4 K-slice
// PARTIALS directly (sums z=4 slices inline, ascending s -- bit-identical to
// the old reduce_f32 + gate chain). Must run BEFORE q_i reuses the buffer.
// ---------------------------------------------------------------------------
__global__ void gate_ln_kernel(const float* __restrict__ P,
                               const float* __restrict__ ba, const float* __restrict__ bb,
                               const float* __restrict__ w, const float* __restrict__ bias,
                               unsigned short* __restrict__ kcb,
                               unsigned short* __restrict__ kcbT) {
  const size_t n = (size_t)S_ * 256;
  int i = blockIdx.x * 256 + threadIdx.x;
  int j = i >> 6, c = i & 63;
  float lg[8], vv[8];
#pragma unroll
  for (int m = 0; m < 4; ++m) {
    if (j == 0) {
      lg[m] = -1e30f + bb[m * C_ + c];
      vv[m] = 0.f;
    } else {
      size_t idxz = (size_t)((j - 1) * 4 + m) * 256 + 192 + c;
      size_t idxc = (size_t)((j - 1) * 4 + m) * 256 + 64 + c;
      float az = P[idxz], ac = P[idxc];
#pragma unroll
      for (int s = 1; s < 4; ++s) { az += P[s * n + idxz]; ac += P[s * n + idxc]; }
      lg[m] = az + bb[m * C_ + c];
      vv[m] = ac;
    }
    size_t idxz2 = (size_t)(j * 4 + m) * 256 + 128 + c;
    size_t idxc2 = (size_t)(j * 4 + m) * 256 + 0 + c;
    float az2 = P[idxz2], ac2 = P[idxc2];
#pragma unroll
    for (int s = 1; s < 4; ++s) { az2 += P[s * n + idxz2]; ac2 += P[s * n + idxc2]; }
    lg[4 + m] = az2 + ba[m * C_ + c];
    vv[4 + m] = ac2;
  }
  float mx = lg[0];
#pragma unroll
  for (int t = 1; t < 8; ++t) mx = fmaxf(mx, lg[t]);
  float se = 0.f, acc = 0.f;
#pragma unroll
  for (int t = 0; t < 8; ++t) {
    float e = expf(lg[t] - mx);
    se += e;
    acc += e * vv[t];
  }
  float cv = acc / se;
  float mu = wave_sum64(cv) * (1.f / 64.f);
  float d = cv - mu;
  float var = wave_sum64(d * d) * (1.f / 64.f);
  float y = d * (1.f / sqrtf(var + EPS_)) * w[c] + bias[c];
  unsigned short h = f2bf(y);
  kcb[(size_t)j * C_ + c] = h;
  kcbT[(size_t)c * NC_ + j] = h;
}

// LN + RoPE for q -> bf16, pre-scaled by 1/sqrt(C)=0.125 (table-driven trig)
__global__ void ln_rope_q_kernel(const float* __restrict__ quq, const float* __restrict__ w,
                                 const float* __restrict__ b, const float* __restrict__ rt,
                                 unsigned short* __restrict__ qb) {
  int row = blockIdx.x * 4 + (threadIdx.x >> 6);  // s*16 + h
  int s = row >> 4;
  int c = threadIdx.x & 63;
  float v = quq[(size_t)row * C_ + c];
  float mu = wave_sum64(v) * (1.f / 64.f);
  float d = v - mu;
  float var = wave_sum64(d * d) * (1.f / 64.f);
  float y = d * (1.f / sqrtf(var + EPS_)) * w[c] + b[c];
  float outv;
  float partner = __shfl_xor(y, 1, 64);
  if (c < C_ - ROPE_) {
    outv = y;
  } else {
    int p = (c - (C_ - ROPE_)) >> 1;
    float cs = rt[(s * 16 + p) * 2];
    float sn = rt[(s * 16 + p) * 2 + 1];
    if ((c & 1) == 0)
      outv = y * cs - partner * sn;
    else
      outv = partner * sn + y * cs;
  }
  qb[(size_t)row * C_ + c] = f2bf(outv * 0.125f);
}

// ---------------------------------------------------------------------------
// Top-512-of-1024 exact radix-select -> selection bitmap, causal-masked.
// ---------------------------------------------------------------------------
#define MINF_ 0x007FFFFFu
__global__ __launch_bounds__(256) void topk_select_kernel(
    const float* __restrict__ isc, unsigned* __restrict__ sel) {
  __shared__ unsigned mv[NC_];
  __shared__ unsigned bins[256];
  __shared__ unsigned wsum[4];
  __shared__ unsigned sB, sR;
  __shared__ unsigned selw[32];
  int s = blockIdx.x;
  int tid = threadIdx.x;
  int w = tid >> 6, lane = tid & 63;
  if (tid < 32) selw[tid] = 0u;
  for (int i = tid; i < NC_; i += 256) {
    if (i < s) {
      unsigned u = __float_as_uint(isc[(size_t)s * NC_ + i]);
      mv[i] = (u & 0x80000000u) ? ~u : (u | 0x80000000u);
    } else {
      mv[i] = MINF_;
    }
  }
  __syncthreads();
  unsigned K_rem = TOPK_;
  unsigned prefix = 0u;
  for (int lvl = 0; lvl < 4; ++lvl) {
    int shift = 24 - 8 * lvl;
    unsigned pm = (lvl == 0) ? 0u : (0xFFFFFFFFu << (32 - 8 * lvl));
    bins[tid] = 0u;
    __syncthreads();
    for (int i = tid; i < NC_; i += 256) {
      unsigned m = mv[i];
      if ((m & pm) == prefix) atomicAdd(&bins[(m >> shift) & 0xFFu], 1u);
    }
    __syncthreads();
    unsigned v = bins[tid];
    unsigned p = v;
#pragma unroll
    for (int off = 1; off < 64; off <<= 1) {
      unsigned n = __shfl_up(p, (unsigned)off, 64);
      if (lane >= off) p += n;
    }
    if (lane == 63) wsum[w] = p;
    __syncthreads();
    unsigned T = 0, woff = 0;
#pragma unroll
    for (int i = 0; i < 4; ++i) {
      unsigned x_ = wsum[i];
      T += x_;
      if (i < w) woff += x_;
    }
    p += woff;
    unsigned gt = T - p;
    if (gt < K_rem && K_rem <= gt + v) { sB = (unsigned)tid; sR = K_rem - gt; }
    __syncthreads();
    prefix |= (sB << shift);
    K_rem = sR;
  }
  unsigned vstar = prefix;
  unsigned eq = 0;
#pragma unroll
  for (int j = 0; j < 4; ++j) eq += (mv[4 * tid + j] == vstar);
  unsigned rp = eq;
#pragma unroll
  for (int off = 1; off < 64; off <<= 1) {
    unsigned n = __shfl_up(rp, (unsigned)off, 64);
    if (lane >= off) rp += n;
  }
  if (lane == 63) wsum[w] = rp;
  __syncthreads();
  unsigned woff2 = 0;
#pragma unroll
  for (int i = 0; i < 4; ++i)
    if (i < w) woff2 += wsum[i];
  unsigned rank0 = rp + woff2 - eq;
  unsigned local = 0, bits = 0;
#pragma unroll
  for (int j = 0; j < 4; ++j) {
    unsigned m = mv[4 * tid + j];
    int idx = 4 * tid + j;
    bool sb = ((m > vstar) || (m == vstar && (rank0 + local) < K_rem)) && (s < 4 * idx);
    local += (m == vstar);
    if (sb) bits |= (1u << (idx & 31));
  }
  if (bits) atomicOr(&selw[tid >> 3], bits);
  __syncthreads();
  if (tid < 32) sel[(size_t)s * 32 + tid] = selw[tid];
}

// ---------------------------------------------------------------------------
// Dense-masked flash attention, ONE WAVE PER BLOCK, FOUR TOKENS PER WAVE:
// K/V fragment loads amortized over 4 tokens (2x fewer loads/token than r11)
// and 4 independent MFMA/exp chains per wave (2x ILP for latency hiding).
// grid 1024, block = 1 wave. Union tile range; out-of-range tokens get e=0
// contributions (exact zeros) -> bit-identical per-token sums. Barrier-free;
// stride-68 p_s (0 conflicts); K/V straight from L2-resident kcb/kcbT.
// ---------------------------------------------------------------------------
#define TS_ 4
__global__ __launch_bounds__(64) void attn_mfma_kernel(
    const unsigned short* __restrict__ qb, const unsigned short* __restrict__ kcb,
    const unsigned short* __restrict__ kcbT, const unsigned* __restrict__ sel,
    const float* __restrict__ sink, unsigned short* __restrict__ out) {
  __shared__ unsigned short p_s[64 * 68];
  __shared__ unsigned selw[TS_][32];
  int tid = threadIdx.x;
  int s0 = blockIdx.x * TS_;
  int lane = tid & 63;
  int qd = lane >> 4, m16 = lane & 15;

  // 64 threads load the 4 tokens' sel rows (wave-private)
#pragma unroll
  for (int i = tid; i < TS_ * 32; i += 64)
    selw[i >> 5][i & 31] = sel[(size_t)(s0 + (i >> 5)) * 32 + (i & 31)];

  short8 qf[4][2];
#pragma unroll
  for (int tk = 0; tk < 4; ++tk)
#pragma unroll
    for (int ks = 0; ks < 2; ++ks)
      qf[tk][ks] = *(const short8*)&qb[(size_t)(s0 + tk) * 1024 + m16 * 64 + ks * 32 + qd * 8];

  floatx4 of[4][4];
#pragma unroll
  for (int i = 0; i < 4; ++i)
#pragma unroll
    for (int j = 0; j < 4; ++j) of[i][j] = (floatx4){0.f, 0.f, 0.f, 0.f};
  float dsum[4] = {0.f, 0.f, 0.f, 0.f};

  int ub = max(511, s0 + TS_ - 2);
  int cs = max(0, (s0 + 4) >> 8);
  int ce = min(16, (ub >> 6) + 1);

  for (int ct = cs; ct < ce; ++ct) {
    int c0 = ct * 64;
#pragma unroll
    for (int mc = 0; mc < 4; ++mc) {
      short8 a0 = *(const short8*)&kcb[(size_t)(c0 + mc * 16 + m16) * 64 + qd * 8];
      short8 a1 = *(const short8*)&kcb[(size_t)(c0 + mc * 16 + m16) * 64 + 32 + qd * 8];
#pragma unroll
      for (int nt = 0; nt < 4; ++nt) {
        floatx4 sc = (floatx4){0.f, 0.f, 0.f, 0.f};
        sc = __builtin_amdgcn_mfma_f32_16x16x32_bf16(a0, qf[nt][0], sc, 0, 0, 0);
        sc = __builtin_amdgcn_mfma_f32_16x16x32_bf16(a1, qf[nt][1], sc, 0, 0, 0);
        unsigned sw = selw[nt][ct * 2 + (mc >> 1)];
        short4v pv;
#pragma unroll
        for (int rg = 0; rg < 4; ++rg) {
          int bitpos = (mc * 16 + qd * 4 + rg) & 31;
          bool ok = ((sw >> bitpos) & 1u) != 0u;
          float e = ok ? __expf(sc[rg]) : 0.f;
          dsum[nt] += e;
          pv[rg] = (short)f2bf(e);
        }
        *(short4v*)&p_s[(nt * 16 + m16) * 68 + mc * 16 + qd * 4] = pv;
      }
    }
#pragma unroll
    for (int ks = 0; ks < 2; ++ks) {
      short8 pa[4];
#pragma unroll
      for (int tk = 0; tk < 4; ++tk)
        pa[tk] = *(const short8*)&p_s[(tk * 16 + m16) * 68 + ks * 32 + qd * 8];
#pragma unroll
      for (int nt = 0; nt < 4; ++nt) {
        short8 bv = *(const short8*)&kcbT[(size_t)(nt * 16 + m16) * NC_ + c0 + ks * 32 + qd * 8];
#pragma unroll
        for (int tk = 0; tk < 4; ++tk)
          of[tk][nt] = __builtin_amdgcn_mfma_f32_16x16x32_bf16(pa[tk], bv, of[tk][nt], 0, 0, 0);
      }
    }
  }
#pragma unroll
  for (int nt = 0; nt < 4; ++nt) {
    dsum[nt] += __shfl_xor(dsum[nt], 16, 64);
    dsum[nt] += __shfl_xor(dsum[nt], 32, 64);
  }
#pragma unroll
  for (int tk = 0; tk < 4; ++tk)
#pragma unroll
    for (int nt = 0; nt < 4; ++nt) {
      floatx4 o = of[tk][nt];
#pragma unroll
      for (int rg = 0; rg < 4; ++rg) {
        int head = qd * 4 + rg;
        float dn = __shfl(dsum[tk], head, 64) + __expf(sink[head]);
        out[(size_t)(s0 + tk) * 1024 + head * 64 + nt * 16 + m16] = f2bf(o[rg] / dn);
      }
    }
}

// ---------------------------------------------------------------------------
// Workspace layout (float offsets)
// ---------------------------------------------------------------------------
#define OFF_QUQ    0u          // quq fp32 / isc / c_q partials
#define OFF_Q      4194304u    // qb bf16
#define OFF_XH     8388608u    // xh bf16
#define OFF_XL     12582912u   // xl bf16 -> sel
#define OFF_PART   16777216u   // k_proj/c4/q_i partials
#define OFF_KO     18874368u   // k_or fp32 (early) -> attnb bf16 (mid)
#define OFF_CQF    22020096u   // qih/qil/kph/kpl overlays
#define OFF_RT     23134208u   // 131072 f : RoPE cos/sin table
#define OFF_WTB    24117248u   // 1048576 f : fused W^T bf16 (2048 x 1024)
#define OFF_CQH    25165824u   // 1048576 f
#define OFF_CQL    26214400u   // 1048576 f
#define OFF_WPACKT 27262976u   // 262144 f
#define OFF_WDQTH  27525120u   // 524288 f
#define OFF_WDQTL  28049408u   // 524288 f
#define OFF_WIUQTH 28573696u   // 65536 f
#define OFF_WIUQTL 28639232u   // 65536 f
#define OFF_WUQT   28704768u   // 262144 f
#define OFF_ODB    28966912u   // 262144 f : o_down bf16
#define OFF_OUPT   29229056u   // 2097152 f
#define OFF_HW     31326208u   // 16384 f
#define OFF_KC     31408128u   // 65536 f : kcb + kcbT
#define OFF_KPR    31473664u   // 65536 f (unused)

extern "C" void kernel_launch(void* const* d_in, const int* in_sizes, int n_in,
                              void* d_out, int out_size, void* d_ws, size_t ws_size,
                              hipStream_t stream) {
  const float* x      = (const float*)d_in[0];
  const float* w_kv_a = (const float*)d_in[1];
  const float* w_kv_b = (const float*)d_in[2];
  const float* w_z_a  = (const float*)d_in[3];
  const float* w_z_b  = (const float*)d_in[4];
  const float* b_a    = (const float*)d_in[5];
  const float* b_b    = (const float*)d_in[6];
  const float* w_dq   = (const float*)d_in[7];
  const float* w_iuq  = (const float*)d_in[8];
  const float* w_w    = (const float*)d_in[9];
  const float* w_k    = (const float*)d_in[10];
  const float* w_uq   = (const float*)d_in[11];
  const float* o_down = (const float*)d_in[12];
  const float* o_up   = (const float*)d_in[13];
  const float* kvn_w  = (const float*)d_in[14];
  const float* kvn_b  = (const float*)d_in[15];
  const float* qn_w   = (const float*)d_in[16];
  const float* qn_b   = (const float*)d_in[17];
  const float* sink   = (const float*)d_in[18];
  float* out = (float*)d_out;
  float* ws = (float*)d_ws;

  float* quq   = ws + OFF_QUQ;
  float* isc   = ws + OFF_QUQ;
  unsigned short* qb = (unsigned short*)(ws + OFF_Q);
  unsigned short* xh = (unsigned short*)(ws + OFF_XH);
  unsigned short* xl = (unsigned short*)(ws + OFF_XL);
  unsigned* sel = (unsigned*)(ws + OFF_XL);
  float* part  = ws + OFF_PART;
  float* k_or  = ws + OFF_KO;
  unsigned short* attnb = (unsigned short*)(ws + OFF_KO);
  unsigned short* qih = (unsigned short*)(ws + OFF_CQF);
  unsigned short* qil = qih + S_ * NHI_ * CI_;
  unsigned short* kph = qil + S_ * NHI_ * CI_;
  unsigned short* kpl = kph + NC_ * CI_;
  float* rt    = ws + OFF_RT;
  unsigned short* wtb = (unsigned short*)(ws + OFF_WTB);
  unsigned short* cqh = (unsigned short*)(ws + OFF_CQH);
  unsigned short* cql = (unsigned short*)(ws + OFF_CQL);
  unsigned short* wpackT = (unsigned short*)(ws + OFF_WPACKT);
  unsigned short* wdqTh  = (unsigned short*)(ws + OFF_WDQTH);
  unsigned short* wdqTl  = (unsigned short*)(ws + OFF_WDQTL);
  unsigned short* wiuqTh = (unsigned short*)(ws + OFF_WIUQTH);
  unsigned short* wiuqTl = (unsigned short*)(ws + OFF_WIUQTL);
  unsigned short* wuqT   = (unsigned short*)(ws + OFF_WUQT);
  unsigned short* odb    = (unsigned short*)(ws + OFF_ODB);
  unsigned short* oupT   = (unsigned short*)(ws + OFF_OUPT);
  float* hw    = ws + OFF_HW;
  unsigned short* kcb  = (unsigned short*)(ws + OFF_KC);
  unsigned short* kcbT = kcb + NC_ * C_;

  dim3 blk(256);

  // --- fused x pass: (hi,lo) split + hw + k_or chunk-mean (one read of x) ---
  cast_split_hw_mean<<<NC_, dim3(512), 0, stream>>>(x, xh, xl, w_w, hw, k_or);
  // --- all weight transposes/casts + rope table in ONE launch ---
  prep_kernel<<<7040, blk, 0, stream>>>(w_kv_a, w_kv_b, w_z_a, w_z_b, wpackT,
                                        w_dq, wdqTh, wdqTl, w_iuq, wiuqTh, wiuqTl,
                                        w_uq, wuqT, o_down, odb, o_up, oupT, rt);

  // --- fused output weight: out = attn @ W (algebraic o_down+o_up fusion) ---
  gemm_bf16_64<<<dim3(2, 32, 4), blk, 0, stream>>>(
      oupT, odb, nullptr, wtb, DG_, D_, DG_, NG_ * 256,
      (long long)DG_, (long long)256 * DG_, 256LL);

  // --- fp32 indexer-side path: k_orig -> k_proj (split-K) + fused cast ---
  gemm_f32_splitk<<<dim3(KSL_, 16), blk, 0, stream>>>(k_or, w_k, part, D_, CI_);
  reduce_splitk_cast<<<256, blk, 0, stream>>>(part, kph, kpl);

  // --- MFMA GEMMs ---
  // c_q: K=2048 -> 4 slices of 512, 128x128 dbuf tile (grid 4x32x4 = 512).
  gemm_bf16_split_128<<<dim3(4, 32, 4), blk, 0, stream>>>(xh, xl, wdqTh, wdqTl, ws,
                                                          512, D_, D_, DC_, 512, 512, (long long)S_ * DC_);
  reduce_cast_split<<<2048, blk, 0, stream>>>(ws, cqh, cql, S_ * DC_, 4);
  // c4: K=2048 -> 4 slices of 512, 128x128 tile (grid 2x32x4 = 256 blocks)
  gemm_bf16_128<<<dim3(2, 32, 4), blk, 0, stream>>>(xh, wpackT, part, nullptr,
                                                    512, D_, D_, 256, 512, 512, (long long)S_ * 256);
  // --- fused gating softmax + LN reads c4 partials directly (before q_i
  //     overwrites the partial buffer) ---
  gate_ln_kernel<<<256, blk, 0, stream>>>(part, b_a, b_b, kvn_w, kvn_b, kcb, kcbT);
  // q_i: K=512 -> 4 slices of 128 (grid 2x64x4 = 512 blocks)
  gemm_bf16_split_64<<<dim3(2, 64, 4), blk, 0, stream>>>(cqh, cql, wiuqTh, wiuqTl, part,
                                                         128, DC_, DC_, 256, 128, 128, (long long)S_ * 256);
  reduce_cast_split<<<1024, blk, 0, stream>>>(part, qih, qil, S_ * 256, 4);
  // quq: 128x128 tile (grid 8x32 = 256 blocks)
  gemm_bf16_128<<<dim3(8, 32, 1), blk, 0, stream>>>(cqh, wuqT, quq, nullptr,
                                                    DC_, DC_, DC_, NH_ * C_, 0, 0, 0);

  // --- q: LN + RoPE (table) -> bf16 scaled by 1/8 ---
  ln_rope_q_kernel<<<16384, blk, 0, stream>>>(quq, qn_w, qn_b, rt, qb);

  // --- indexer scores (split-bf16 MFMA, causal tile skip) + radix-select ---
  iscores_mfma<<<dim3(8, 128), blk, 0, stream>>>(qih, qil, kph, kpl, hw, isc);
  topk_select_kernel<<<S_, blk, 0, stream>>>(isc, sel);

  // --- dense-masked flash attention (1 wave/block, 4 tokens/wave) ---
  attn_mfma_kernel<<<S_ / TS_, dim3(64), 0, stream>>>(qb, kcb, kcbT, sel, sink, attnb);

  // --- fused output projection: out = attn @ W (128x128 dbuf, XCD-swizzled) ---
  gemm_bf16_128<<<dim3(16, 32, 1), blk, 0, stream>>>(attnb, wtb, out, nullptr,
                                                     NG_ * 256, NH_ * C_, NG_ * 256, D_, 0, 0, 0);
}

// Round 13
// 384.525 us; speedup vs baseline: 1.0400x; 1.0400x over previous
//
#include <hip/hip_runtime.h>
#include <math.h>

// Problem constants (B=1 throughout)
#define S_   4096
#define D_   2048
#define M_   4
#define NC_  1024
#define TOPK_ 512
#define NH_  16
#define C_   64
#define DC_  512
#define NG_  4
#define DG_  512
#define CI_  64
#define NHI_ 4
#define ROPE_ 32
#define EPS_ 1e-6f

typedef __attribute__((ext_vector_type(8))) short short8;
typedef __attribute__((ext_vector_type(4))) short short4v;
typedef __attribute__((ext_vector_type(4))) float floatx4;

__device__ inline unsigned short f2bf(float f) {
  unsigned u = __float_as_uint(f);
  u += 0x7fff + ((u >> 16) & 1);   // round-to-nearest-even
  return (unsigned short)(u >> 16);
}
__device__ inline float bf2f(unsigned short h) {
  return __uint_as_float(((unsigned)h) << 16);
}

#define GLD16(src, dst) __builtin_amdgcn_global_load_lds( \
    (const __attribute__((address_space(1))) unsigned int*)(src), \
    (__attribute__((address_space(3))) unsigned int*)(dst), 16, 0, 0)

// Bijective XCD-chunk swizzle (T1): blocks sharing an A-panel (consecutive
// flat ids, x-fastest) land on the SAME XCD L2. Requires nwg % 8 == 0.
__device__ inline void xcd_remap(int& bx, int& by, int& bz) {
  int nx = gridDim.x, ny = gridDim.y;
  int flat = blockIdx.x + nx * (blockIdx.y + ny * blockIdx.z);
  int nwg = nx * ny * (int)gridDim.z;
  int swz = (flat & 7) * (nwg >> 3) + (flat >> 3);
  bx = swz % nx;
  int t = swz / nx;
  by = t % ny;
  bz = t / ny;
}

// ---------------------------------------------------------------------------
// bf16 MFMA GEMM, 64x128 tile (4 waves x 32x64). C = A @ Bt^T, grid.z strides.
// Double-buffered LDS, BK=64, ONE barrier/K-tile. XCD-swizzled.
// ---------------------------------------------------------------------------
__global__ __launch_bounds__(256) void gemm_bf16_64(
    const unsigned short* __restrict__ A, const unsigned short* __restrict__ Bt,
    float* __restrict__ Cf, unsigned short* __restrict__ Cb,
    int K, int lda, int ldb, int ldc,
    long long Az, long long Bz, long long Cz) {
  int bx, by, zz;
  xcd_remap(bx, by, zz);
  A += (size_t)zz * Az;
  Bt += (size_t)zz * Bz;
  if (Cf) Cf += (size_t)zz * Cz;
  if (Cb) Cb += (size_t)zz * Cz;
  __shared__ unsigned short As[2 * 2 * 64 * 32];    // 16 KB
  __shared__ unsigned short Bs[2 * 2 * 128 * 32];   // 32 KB
  int tid = threadIdx.x;
  int bm = by * 64, bn = bx * 128;
  int lane = tid & 63, wid = tid >> 6;
  int wm = (wid & 1) * 32, wn = (wid >> 1) * 64;
  int qd = lane >> 4, m16 = lane & 15;

  floatx4 acc[2][4];
#pragma unroll
  for (int i = 0; i < 2; ++i)
#pragma unroll
    for (int j = 0; j < 4; ++j) acc[i][j] = (floatx4){0.f, 0.f, 0.f, 0.f};

  auto stage = [&](int buf, int kt) {
#pragma unroll
    for (int h = 0; h < 2; ++h) {
      {
        int rr = tid >> 2, ss = tid & 3;
        int gg = ss ^ ((rr >> 1) & 3);
        GLD16(A + (size_t)(bm + rr) * lda + kt + h * 32 + gg * 8,
              &As[(buf * 2 + h) * 2048 + tid * 8]);
      }
#pragma unroll
      for (int i = 0; i < 2; ++i) {
        int idx = tid + 256 * i;
        int rr = idx >> 2, ss = idx & 3;
        int gg = ss ^ ((rr >> 1) & 3);
        GLD16(Bt + (size_t)(bn + rr) * ldb + kt + h * 32 + gg * 8,
              &Bs[(buf * 2 + h) * 4096 + idx * 8]);
      }
    }
  };
  auto compute = [&](int buf) {
#pragma unroll
    for (int h = 0; h < 2; ++h) {
      const unsigned short* Ab = &As[(buf * 2 + h) * 2048];
      const unsigned short* Bb = &Bs[(buf * 2 + h) * 4096];
      short8 af[2], bfr[4];
#pragma unroll
      for (int mi = 0; mi < 2; ++mi) {
        int r = wm + mi * 16 + m16;
        int slot = qd ^ ((r >> 1) & 3);
        af[mi] = *(const short8*)&Ab[r * 32 + slot * 8];
      }
#pragma unroll
      for (int ni = 0; ni < 4; ++ni) {
        int r = wn + ni * 16 + m16;
        int slot = qd ^ ((r >> 1) & 3);
        bfr[ni] = *(const short8*)&Bb[r * 32 + slot * 8];
      }
#pragma unroll
      for (int mi = 0; mi < 2; ++mi)
#pragma unroll
        for (int ni = 0; ni < 4; ++ni)
          acc[mi][ni] = __builtin_amdgcn_mfma_f32_16x16x32_bf16(af[mi], bfr[ni], acc[mi][ni], 0, 0, 0);
    }
  };

  stage(0, 0);
  __syncthreads();
  int cur = 0;
  for (int kt = 64; kt < K; kt += 64) {
    stage(cur ^ 1, kt);
    compute(cur);
    __syncthreads();
    cur ^= 1;
  }
  compute(cur);

#pragma unroll
  for (int mi = 0; mi < 2; ++mi)
#pragma unroll
    for (int ni = 0; ni < 4; ++ni) {
      int col = bn + wn + ni * 16 + m16;
#pragma unroll
      for (int rg = 0; rg < 4; ++rg) {
        int row = bm + wm + mi * 16 + qd * 4 + rg;
        if (Cb)
          Cb[(size_t)row * ldc + col] = f2bf(acc[mi][ni][rg]);
        else
          Cf[(size_t)row * ldc + col] = acc[mi][ni][rg];
      }
    }
}

// ---------------------------------------------------------------------------
// bf16 MFMA GEMM, 128x128 tile (4 waves x 64x64). C = A @ Bt^T, grid.z strides.
// Double-buffered LDS, BK=64, ONE barrier/K-tile. XCD-swizzled.
// ---------------------------------------------------------------------------
__global__ __launch_bounds__(256) void gemm_bf16_128(
    const unsigned short* __restrict__ A, const unsigned short* __restrict__ Bt,
    float* __restrict__ Cf, unsigned short* __restrict__ Cb,
    int K, int lda, int ldb, int ldc,
    long long Az, long long Bz, long long Cz) {
  int bx, by, zz;
  xcd_remap(bx, by, zz);
  A += (size_t)zz * Az;
  Bt += (size_t)zz * Bz;
  if (Cf) Cf += (size_t)zz * Cz;
  if (Cb) Cb += (size_t)zz * Cz;
  __shared__ unsigned short As[2 * 2 * 128 * 32];   // 32 KB
  __shared__ unsigned short Bs[2 * 2 * 128 * 32];   // 32 KB
  int tid = threadIdx.x;
  int bm = by * 128, bn = bx * 128;
  int lane = tid & 63, wid = tid >> 6;
  int wm = (wid & 1) * 64, wn = (wid >> 1) * 64;
  int qd = lane >> 4, m16 = lane & 15;

  floatx4 acc[4][4];
#pragma unroll
  for (int i = 0; i < 4; ++i)
#pragma unroll
    for (int j = 0; j < 4; ++j) acc[i][j] = (floatx4){0.f, 0.f, 0.f, 0.f};

  auto stage = [&](int buf, int kt) {
#pragma unroll
    for (int h = 0; h < 2; ++h) {
#pragma unroll
      for (int i = 0; i < 2; ++i) {
        int idx = tid + 256 * i;
        int rr = idx >> 2, ss = idx & 3;
        int gg = ss ^ ((rr >> 1) & 3);
        GLD16(A + (size_t)(bm + rr) * lda + kt + h * 32 + gg * 8,
              &As[(buf * 2 + h) * 4096 + idx * 8]);
        GLD16(Bt + (size_t)(bn + rr) * ldb + kt + h * 32 + gg * 8,
              &Bs[(buf * 2 + h) * 4096 + idx * 8]);
      }
    }
  };
  auto compute = [&](int buf) {
#pragma unroll
    for (int h = 0; h < 2; ++h) {
      const unsigned short* Ab = &As[(buf * 2 + h) * 4096];
      const unsigned short* Bb = &Bs[(buf * 2 + h) * 4096];
      short8 af[4], bfr[4];
#pragma unroll
      for (int mi = 0; mi < 4; ++mi) {
        int r = wm + mi * 16 + m16;
        int slot = qd ^ ((r >> 1) & 3);
        af[mi] = *(const short8*)&Ab[r * 32 + slot * 8];
      }
#pragma unroll
      for (int ni = 0; ni < 4; ++ni) {
        int r = wn + ni * 16 + m16;
        int slot = qd ^ ((r >> 1) & 3);
        bfr[ni] = *(const short8*)&Bb[r * 32 + slot * 8];
      }
#pragma unroll
      for (int mi = 0; mi < 4; ++mi)
#pragma unroll
        for (int ni = 0; ni < 4; ++ni)
          acc[mi][ni] = __builtin_amdgcn_mfma_f32_16x16x32_bf16(af[mi], bfr[ni], acc[mi][ni], 0, 0, 0);
    }
  };

  stage(0, 0);
  __syncthreads();
  int cur = 0;
  for (int kt = 64; kt < K; kt += 64) {
    stage(cur ^ 1, kt);
    compute(cur);
    __syncthreads();
    cur ^= 1;
  }
  compute(cur);

#pragma unroll
  for (int mi = 0; mi < 4; ++mi)
#pragma unroll
    for (int ni = 0; ni < 4; ++ni) {
      int col = bn + wn + ni * 16 + m16;
#pragma unroll
      for (int rg = 0; rg < 4; ++rg) {
        int row = bm + wm + mi * 16 + qd * 4 + rg;
        if (Cb)
          Cb[(size_t)row * ldc + col] = f2bf(acc[mi][ni][rg]);
        else
          Cf[(size_t)row * ldc + col] = acc[mi][ni][rg];
      }
    }
}

// ---------------------------------------------------------------------------
// Split-bf16 MFMA GEMM, 64x128 tile (fp32-accurate, 3 MFMA terms).
// ---------------------------------------------------------------------------
__global__ __launch_bounds__(256) void gemm_bf16_split_64(
    const unsigned short* __restrict__ Ah, const unsigned short* __restrict__ Al,
    const unsigned short* __restrict__ Bh, const unsigned short* __restrict__ Bl,
    float* __restrict__ Cf, int K, int lda, int ldb, int ldc,
    long long Az, long long Bz, long long Cz) {
  int bx, by, zz;
  xcd_remap(bx, by, zz);
  Ah += (size_t)zz * Az; Al += (size_t)zz * Az;
  Bh += (size_t)zz * Bz; Bl += (size_t)zz * Bz;
  Cf += (size_t)zz * Cz;
  __shared__ unsigned short Ash[64 * 32];
  __shared__ unsigned short Asl[64 * 32];
  __shared__ unsigned short Bsh[128 * 32];
  __shared__ unsigned short Bsl[128 * 32];
  int tid = threadIdx.x;
  int bm = by * 64, bn = bx * 128;
  int lane = tid & 63, wid = tid >> 6;
  int wm = (wid & 1) * 32, wn = (wid >> 1) * 64;
  int qd = lane >> 4, m16 = lane & 15;

  floatx4 acc[2][4];
#pragma unroll
  for (int i = 0; i < 2; ++i)
#pragma unroll
    for (int j = 0; j < 4; ++j) acc[i][j] = (floatx4){0.f, 0.f, 0.f, 0.f};

  for (int k0 = 0; k0 < K; k0 += 32) {
    {
      int r = tid >> 2, sl = tid & 3;
      int g = sl ^ ((r >> 1) & 3);
      size_t aoff = (size_t)(bm + r) * lda + k0 + g * 8;
      GLD16(Ah + aoff, &Ash[tid * 8]);
      GLD16(Al + aoff, &Asl[tid * 8]);
    }
#pragma unroll
    for (int i = 0; i < 2; ++i) {
      int idx = tid + 256 * i;
      int r = idx >> 2, sl = idx & 3;
      int g = sl ^ ((r >> 1) & 3);
      size_t boff = (size_t)(bn + r) * ldb + k0 + g * 8;
      GLD16(Bh + boff, &Bsh[idx * 8]);
      GLD16(Bl + boff, &Bsl[idx * 8]);
    }
    __syncthreads();
    short8 afh[2], afl[2], bfh[4], bfl[4];
#pragma unroll
    for (int mi = 0; mi < 2; ++mi) {
      int r = wm + mi * 16 + m16;
      int slot = qd ^ ((r >> 1) & 3);
      afh[mi] = *(const short8*)&Ash[r * 32 + slot * 8];
      afl[mi] = *(const short8*)&Asl[r * 32 + slot * 8];
    }
#pragma unroll
    for (int ni = 0; ni < 4; ++ni) {
      int r = wn + ni * 16 + m16;
      int slot = qd ^ ((r >> 1) & 3);
      bfh[ni] = *(const short8*)&Bsh[r * 32 + slot * 8];
      bfl[ni] = *(const short8*)&Bsl[r * 32 + slot * 8];
    }
#pragma unroll
    for (int mi = 0; mi < 2; ++mi)
#pragma unroll
      for (int ni = 0; ni < 4; ++ni) {
        acc[mi][ni] = __builtin_amdgcn_mfma_f32_16x16x32_bf16(afh[mi], bfh[ni], acc[mi][ni], 0, 0, 0);
        acc[mi][ni] = __builtin_amdgcn_mfma_f32_16x16x32_bf16(afh[mi], bfl[ni], acc[mi][ni], 0, 0, 0);
        acc[mi][ni] = __builtin_amdgcn_mfma_f32_16x16x32_bf16(afl[mi], bfh[ni], acc[mi][ni], 0, 0, 0);
      }
    __syncthreads();
  }
#pragma unroll
  for (int mi = 0; mi < 2; ++mi)
#pragma unroll
    for (int ni = 0; ni < 4; ++ni) {
      int col = bn + wn + ni * 16 + m16;
#pragma unroll
      for (int rg = 0; rg < 4; ++rg) {
        int row = bm + wm + mi * 16 + qd * 4 + rg;
        Cf[(size_t)row * ldc + col] = acc[mi][ni][rg];
      }
    }
}

// ---------------------------------------------------------------------------
// Split-bf16 MFMA GEMM, 128x128 tile (fp32-accurate, 3 MFMA terms).
// Double-buffered LDS, BK=32, ONE barrier/K-tile.
// ---------------------------------------------------------------------------
__global__ __launch_bounds__(256) void gemm_bf16_split_128(
    const unsigned short* __restrict__ Ah, const unsigned short* __restrict__ Al,
    const unsigned short* __restrict__ Bh, const unsigned short* __restrict__ Bl,
    float* __restrict__ Cf, int K, int lda, int ldb, int ldc,
    long long Az, long long Bz, long long Cz) {
  int bx, by, zz;
  xcd_remap(bx, by, zz);
  Ah += (size_t)zz * Az; Al += (size_t)zz * Az;
  Bh += (size_t)zz * Bz; Bl += (size_t)zz * Bz;
  Cf += (size_t)zz * Cz;
  __shared__ unsigned short Ash[2 * 128 * 32];   // 16 KB each
  __shared__ unsigned short Asl[2 * 128 * 32];
  __shared__ unsigned short Bsh[2 * 128 * 32];
  __shared__ unsigned short Bsl[2 * 128 * 32];
  int tid = threadIdx.x;
  int bm = by * 128, bn = bx * 128;
  int lane = tid & 63, wid = tid >> 6;
  int wm = (wid & 1) * 64, wn = (wid >> 1) * 64;
  int qd = lane >> 4, m16 = lane & 15;

  floatx4 acc[4][4];
#pragma unroll
  for (int i = 0; i < 4; ++i)
#pragma unroll
    for (int j = 0; j < 4; ++j) acc[i][j] = (floatx4){0.f, 0.f, 0.f, 0.f};

  auto stage = [&](int buf, int kt) {
#pragma unroll
    for (int i = 0; i < 2; ++i) {
      int idx = tid + 256 * i;
      int rr = idx >> 2, ss = idx & 3;
      int gg = ss ^ ((rr >> 1) & 3);
      size_t aoff = (size_t)(bm + rr) * lda + kt + gg * 8;
      size_t boff = (size_t)(bn + rr) * ldb + kt + gg * 8;
      GLD16(Ah + aoff, &Ash[buf * 4096 + idx * 8]);
      GLD16(Al + aoff, &Asl[buf * 4096 + idx * 8]);
      GLD16(Bh + boff, &Bsh[buf * 4096 + idx * 8]);
      GLD16(Bl + boff, &Bsl[buf * 4096 + idx * 8]);
    }
  };
  auto compute = [&](int buf) {
    const unsigned short* Ahb = &Ash[buf * 4096];
    const unsigned short* Alb = &Asl[buf * 4096];
    const unsigned short* Bhb = &Bsh[buf * 4096];
    const unsigned short* Blb = &Bsl[buf * 4096];
    short8 afh[4], afl[4], bfh[4], bfl[4];
#pragma unroll
    for (int mi = 0; mi < 4; ++mi) {
      int r = wm + mi * 16 + m16;
      int slot = qd ^ ((r >> 1) & 3);
      afh[mi] = *(const short8*)&Ahb[r * 32 + slot * 8];
      afl[mi] = *(const short8*)&Alb[r * 32 + slot * 8];
    }
#pragma unroll
    for (int ni = 0; ni < 4; ++ni) {
      int r = wn + ni * 16 + m16;
      int slot = qd ^ ((r >> 1) & 3);
      bfh[ni] = *(const short8*)&Bhb[r * 32 + slot * 8];
      bfl[ni] = *(const short8*)&Blb[r * 32 + slot * 8];
    }
#pragma unroll
    for (int mi = 0; mi < 4; ++mi)
#pragma unroll
      for (int ni = 0; ni < 4; ++ni) {
        acc[mi][ni] = __builtin_amdgcn_mfma_f32_16x16x32_bf16(afh[mi], bfh[ni], acc[mi][ni], 0, 0, 0);
        acc[mi][ni] = __builtin_amdgcn_mfma_f32_16x16x32_bf16(afh[mi], bfl[ni], acc[mi][ni], 0, 0, 0);
        acc[mi][ni] = __builtin_amdgcn_mfma_f32_16x16x32_bf16(afl[mi], bfh[ni], acc[mi][ni], 0, 0, 0);
      }
  };

  stage(0, 0);
  __syncthreads();
  int cur = 0;
  for (int kt = 32; kt < K; kt += 32) {
    stage(cur ^ 1, kt);
    compute(cur);
    __syncthreads();
    cur ^= 1;
  }
  compute(cur);

#pragma unroll
  for (int mi = 0; mi < 4; ++mi)
#pragma unroll
    for (int ni = 0; ni < 4; ++ni) {
      int col = bn + wn + ni * 16 + m16;
#pragma unroll
      for (int rg = 0; rg < 4; ++rg) {
        int row = bm + wm + mi * 16 + qd * 4 + rg;
        Cf[(size_t)row * ldc + col] = acc[mi][ni][rg];
      }
    }
}

// reduce z fp32 slices -> (bf16 hi, bf16 lo)
__global__ void reduce_cast_split(const float* __restrict__ P, unsigned short* __restrict__ hi,
                                  unsigned short* __restrict__ lo, int n, int z) {
  int i = (blockIdx.x * 256 + threadIdx.x) * 4;
  if (i >= n) return;
  float4 a = *(const float4*)&P[i];
  for (int s = 1; s < z; ++s) {
    float4 b = *(const float4*)&P[(size_t)s * n + i];
    a.x += b.x; a.y += b.y; a.z += b.z; a.w += b.w;
  }
  ushort4 h = make_ushort4(f2bf(a.x), f2bf(a.y), f2bf(a.z), f2bf(a.w));
  ushort4 l = make_ushort4(f2bf(a.x - bf2f(h.x)), f2bf(a.y - bf2f(h.y)),
                           f2bf(a.z - bf2f(h.z)), f2bf(a.w - bf2f(h.w)));
  *(ushort4*)&hi[i] = h;
  *(ushort4*)&lo[i] = l;
}

// ---------------------------------------------------------------------------
// Indexer scores on split-bf16 MFMA (relu*hw epilogue in-register).
// ---------------------------------------------------------------------------
__global__ __launch_bounds__(256) void iscores_mfma(
    const unsigned short* __restrict__ Ah, const unsigned short* __restrict__ Al,
    const unsigned short* __restrict__ Bh, const unsigned short* __restrict__ Bl,
    const float* __restrict__ hw, float* __restrict__ isc) {
  int bm = blockIdx.y * 128, bn = blockIdx.x * 128;
  if (bn > (bm >> 2) + 30) return;
  __shared__ unsigned short Ash[128 * 32];
  __shared__ unsigned short Asl[128 * 32];
  __shared__ unsigned short Bsh[128 * 32];
  __shared__ unsigned short Bsl[128 * 32];
  int tid = threadIdx.x;
  int lane = tid & 63, wid = tid >> 6;
  int wm = (wid >> 1) * 64, wn = (wid & 1) * 64;
  int qd = lane >> 4, m16 = lane & 15;

  floatx4 acc[4][4];
#pragma unroll
  for (int i = 0; i < 4; ++i)
#pragma unroll
    for (int j = 0; j < 4; ++j) acc[i][j] = (floatx4){0.f, 0.f, 0.f, 0.f};

#pragma unroll
  for (int k0 = 0; k0 < 64; k0 += 32) {
#pragma unroll
    for (int i = 0; i < 2; ++i) {
      int idx = tid + 256 * i;
      int r = idx >> 2, s = idx & 3;
      int g = s ^ ((r >> 1) & 3);
      size_t aoff = (size_t)(bm + r) * 64 + k0 + g * 8;
      size_t boff = (size_t)(bn + r) * 64 + k0 + g * 8;
      GLD16(Ah + aoff, &Ash[idx * 8]);
      GLD16(Al + aoff, &Asl[idx * 8]);
      GLD16(Bh + boff, &Bsh[idx * 8]);
      GLD16(Bl + boff, &Bsl[idx * 8]);
    }
    __syncthreads();
    short8 afh[4], afl[4], bfh[4], bfl[4];
#pragma unroll
    for (int mi = 0; mi < 4; ++mi) {
      int r = wm + mi * 16 + m16;
      int slot = qd ^ ((r >> 1) & 3);
      afh[mi] = *(const short8*)&Ash[r * 32 + slot * 8];
      afl[mi] = *(const short8*)&Asl[r * 32 + slot * 8];
    }
#pragma unroll
    for (int ni = 0; ni < 4; ++ni) {
      int r = wn + ni * 16 + m16;
      int slot = qd ^ ((r >> 1) & 3);
      bfh[ni] = *(const short8*)&Bsh[r * 32 + slot * 8];
      bfl[ni] = *(const short8*)&Bsl[r * 32 + slot * 8];
    }
#pragma unroll
    for (int mi = 0; mi < 4; ++mi)
#pragma unroll
      for (int ni = 0; ni < 4; ++ni) {
        acc[mi][ni] = __builtin_amdgcn_mfma_f32_16x16x32_bf16(afh[mi], bfh[ni], acc[mi][ni], 0, 0, 0);
        acc[mi][ni] = __builtin_amdgcn_mfma_f32_16x16x32_bf16(afh[mi], bfl[ni], acc[mi][ni], 0, 0, 0);
        acc[mi][ni] = __builtin_amdgcn_mfma_f32_16x16x32_bf16(afl[mi], bfh[ni], acc[mi][ni], 0, 0, 0);
      }
    __syncthreads();
  }
#pragma unroll
  for (int mi = 0; mi < 4; ++mi) {
    int tok = ((bm + wm + mi * 16) >> 2) + qd;
    float4 hwv = *(const float4*)&hw[tok * 4];
#pragma unroll
    for (int ni = 0; ni < 4; ++ni) {
      floatx4 a = acc[mi][ni];
      float v = fmaxf(a[0], 0.f) * hwv.x + fmaxf(a[1], 0.f) * hwv.y +
                fmaxf(a[2], 0.f) * hwv.z + fmaxf(a[3], 0.f) * hwv.w;
      int col = bn + wn + ni * 16 + m16;
      isc[(size_t)tok * NC_ + col] = (col < tok) ? v : -__builtin_inff();
    }
  }
}

// ---------------------------------------------------------------------------
// Split-K fp32 GEMM for k_proj (N=64) + fused reduce+cast_split
// ---------------------------------------------------------------------------
#define BM 64
#define BN 64
#define BK 16
#define KSL_ 16
#define KSLICE_ 128
__global__ __launch_bounds__(256) void gemm_f32_splitk(
    const float* __restrict__ A, const float* __restrict__ B,
    float* __restrict__ P, int lda, int ldb) {
  __shared__ float As[BK][BM + 4];
  __shared__ float Bs[BK][BN + 4];
  int tid = threadIdx.x;
  int bm = blockIdx.y * BM;
  int kbase = blockIdx.x * KSLICE_;
  int tr = tid >> 4;
  int tc = tid & 15;
  float acc[4][4] = {{0.f}};
  for (int k0 = kbase; k0 < kbase + KSLICE_; k0 += BK) {
    int ac = tid & 15;
    int ar0 = tid >> 4;
#pragma unroll
    for (int i = 0; i < 4; ++i) {
      int r = ar0 + 16 * i;
      As[ac][r] = A[(size_t)(bm + r) * lda + k0 + ac];
    }
    int bc = tid & 63;
    int br0 = tid >> 6;
#pragma unroll
    for (int i = 0; i < 4; ++i) {
      int r = br0 + 4 * i;
      Bs[r][bc] = B[(size_t)(k0 + r) * ldb + bc];
    }
    __syncthreads();
#pragma unroll
    for (int kk = 0; kk < BK; ++kk) {
      float4 av = *(const float4*)&As[kk][tr * 4];
      float4 bv = *(const float4*)&Bs[kk][tc * 4];
      float a[4] = {av.x, av.y, av.z, av.w};
      float b[4] = {bv.x, bv.y, bv.z, bv.w};
#pragma unroll
      for (int i = 0; i < 4; ++i)
#pragma unroll
        for (int j = 0; j < 4; ++j) acc[i][j] += a[i] * b[j];
    }
    __syncthreads();
  }
  float* Pb = P + (size_t)blockIdx.x * (NC_ * CI_);
#pragma unroll
  for (int i = 0; i < 4; ++i) {
    float4 v = make_float4(acc[i][0], acc[i][1], acc[i][2], acc[i][3]);
    *(float4*)&Pb[(size_t)(bm + tr * 4 + i) * CI_ + tc * 4] = v;
  }
}

// fused: reduce 16 split-K slices -> (bf16 hi, bf16 lo) directly (no k_pr)
__global__ void reduce_splitk_cast(const float* __restrict__ P,
                                   unsigned short* __restrict__ hi,
                                   unsigned short* __restrict__ lo) {
  int i = blockIdx.x * 256 + threadIdx.x;
  float a = 0.f;
#pragma unroll
  for (int s = 0; s < KSL_; ++s) a += P[(size_t)s * (NC_ * CI_) + i];
  unsigned short h = f2bf(a);
  hi[i] = h;
  lo[i] = f2bf(a - bf2f(h));
}

__device__ inline float wave_sum64(float v) {
#pragma unroll
  for (int off = 32; off > 0; off >>= 1) v += __shfl_xor(v, off, 64);
  return v;
}

// Fused: x -> (hi, lo) split, hw = x @ w_w, AND k_or chunk mean.
__global__ __launch_bounds__(512) void cast_split_hw_mean(
    const float* __restrict__ x, unsigned short* __restrict__ hi,
    unsigned short* __restrict__ lo, const float* __restrict__ ww,
    float* __restrict__ hw, float* __restrict__ ko) {
  int j = blockIdx.x, tid = threadIdx.x;
  int d0 = tid * 4;
  const float* wr = ww + d0 * 4;
  float4 v[4];
  float a[4][4];
#pragma unroll
  for (int m = 0; m < 4; ++m) {
    size_t i = (size_t)(j * 4 + m) * D_ + d0;
    v[m] = *(const float4*)&x[i];
    ushort4 h = make_ushort4(f2bf(v[m].x), f2bf(v[m].y), f2bf(v[m].z), f2bf(v[m].w));
    ushort4 l = make_ushort4(f2bf(v[m].x - bf2f(h.x)), f2bf(v[m].y - bf2f(h.y)),
                             f2bf(v[m].z - bf2f(h.z)), f2bf(v[m].w - bf2f(h.w)));
    *(ushort4*)&hi[i] = h;
    *(ushort4*)&lo[i] = l;
    a[m][0] = v[m].x * wr[0] + v[m].y * wr[4] + v[m].z * wr[8]  + v[m].w * wr[12];
    a[m][1] = v[m].x * wr[1] + v[m].y * wr[5] + v[m].z * wr[9]  + v[m].w * wr[13];
    a[m][2] = v[m].x * wr[2] + v[m].y * wr[6] + v[m].z * wr[10] + v[m].w * wr[14];
    a[m][3] = v[m].x * wr[3] + v[m].y * wr[7] + v[m].z * wr[11] + v[m].w * wr[15];
  }
  float4 s4;
  s4.x = 0.25f * (v[0].x + v[1].x + v[2].x + v[3].x);
  s4.y = 0.25f * (v[0].y + v[1].y + v[2].y + v[3].y);
  s4.z = 0.25f * (v[0].z + v[1].z + v[2].z + v[3].z);
  s4.w = 0.25f * (v[0].w + v[1].w + v[2].w + v[3].w);
  *(float4*)&ko[(size_t)j * D_ + d0] = s4;
#pragma unroll
  for (int m = 0; m < 4; ++m)
#pragma unroll
    for (int h2 = 0; h2 < 4; ++h2) a[m][h2] = wave_sum64(a[m][h2]);
  __shared__ float red[8][16];
  int wid = tid >> 6, lane = tid & 63;
  if (lane == 0) {
#pragma unroll
    for (int m = 0; m < 4; ++m)
#pragma unroll
      for (int h2 = 0; h2 < 4; ++h2) red[wid][m * 4 + h2] = a[m][h2];
  }
  __syncthreads();
  if (tid < 16) {
    float acc = 0.f;
#pragma unroll
    for (int w2 = 0; w2 < 8; ++w2) acc += red[w2][tid];
    hw[(size_t)(j * 4 + (tid >> 2)) * 4 + (tid & 3)] = acc;
  }
}

// ---------------------------------------------------------------------------
// PREP megakernel: 10 preprocessing launches fused into one (block ranges).
// ---------------------------------------------------------------------------
__global__ __launch_bounds__(256) void prep_kernel(
    const float* __restrict__ w_kv_a, const float* __restrict__ w_kv_b,
    const float* __restrict__ w_z_a, const float* __restrict__ w_z_b,
    unsigned short* __restrict__ wpackT,
    const float* __restrict__ w_dq, unsigned short* __restrict__ wdqTh,
    unsigned short* __restrict__ wdqTl,
    const float* __restrict__ w_iuq, unsigned short* __restrict__ wiuqTh,
    unsigned short* __restrict__ wiuqTl,
    const float* __restrict__ w_uq, unsigned short* __restrict__ wuqT,
    const float* __restrict__ o_down, unsigned short* __restrict__ odb,
    const float* __restrict__ o_up, unsigned short* __restrict__ oupT,
    float* __restrict__ rt) {
  __shared__ float t[32][33];
  int b = blockIdx.x;
  int tid = threadIdx.x;
  int tx = tid & 31, ty = tid >> 5;
  if (b < 512) {
    int wsel = b >> 7, local = b & 127;
    int bx = local & 63, by = local >> 6;
    const float* in = (wsel == 0) ? w_kv_a : (wsel == 1) ? w_kv_b : (wsel == 2) ? w_z_a : w_z_b;
    unsigned short* outp = wpackT + wsel * 64 * 2048;
    int k0 = bx * 32, n0 = by * 32;
#pragma unroll
    for (int i = 0; i < 4; ++i)
      t[ty * 4 + i][tx] = in[(size_t)(k0 + ty * 4 + i) * 64 + n0 + tx];
    __syncthreads();
#pragma unroll
    for (int i = 0; i < 4; ++i)
      outp[(size_t)(n0 + ty * 4 + i) * 2048 + k0 + tx] = f2bf(t[tx][ty * 4 + i]);
  } else if (b < 1536) {
    int local = b - 512;
    int bx = local & 63, by = local >> 6;
    int k0 = bx * 32, n0 = by * 32;
#pragma unroll
    for (int i = 0; i < 4; ++i)
      t[ty * 4 + i][tx] = w_dq[(size_t)(k0 + ty * 4 + i) * 512 + n0 + tx];
    __syncthreads();
#pragma unroll
    for (int i = 0; i < 4; ++i) {
      float v = t[tx][ty * 4 + i];
      unsigned short h = f2bf(v);
      wdqTh[(size_t)(n0 + ty * 4 + i) * 2048 + k0 + tx] = h;
      wdqTl[(size_t)(n0 + ty * 4 + i) * 2048 + k0 + tx] = f2bf(v - bf2f(h));
    }
  } else if (b < 1664) {
    int local = b - 1536;
    int bx = local & 15, by = local >> 4;
    int k0 = bx * 32, n0 = by * 32;
#pragma unroll
    for (int i = 0; i < 4; ++i)
      t[ty * 4 + i][tx] = w_iuq[(size_t)(k0 + ty * 4 + i) * 256 + n0 + tx];
    __syncthreads();
#pragma unroll
    for (int i = 0; i < 4; ++i) {
      float v = t[tx][ty * 4 + i];
      unsigned short h = f2bf(v);
      wiuqTh[(size_t)(n0 + ty * 4 + i) * 512 + k0 + tx] = h;
      wiuqTl[(size_t)(n0 + ty * 4 + i) * 512 + k0 + tx] = f2bf(v - bf2f(h));
    }
  } else if (b < 2176) {
    int local = b - 1664;
    int bx = local & 15, by = local >> 4;
    int k0 = bx * 32, n0 = by * 32;
#pragma unroll
    for (int i = 0; i < 4; ++i)
      t[ty * 4 + i][tx] = w_uq[(size_t)(k0 + ty * 4 + i) * 1024 + n0 + tx];
    __syncthreads();
#pragma unroll
    for (int i = 0; i < 4; ++i)
      wuqT[(size_t)(n0 + ty * 4 + i) * 512 + k0 + tx] = f2bf(t[tx][ty * 4 + i]);
  } else if (b < 2688) {
    int i = ((b - 2176) * 256 + tid) * 4;
    float4 v = *(const float4*)&o_down[i];
    ushort4 o = make_ushort4(f2bf(v.x), f2bf(v.y), f2bf(v.z), f2bf(v.w));
    *(ushort4*)&odb[i] = o;
  } else if (b < 6784) {
    int local = b - 2688;
    int bx = local & 63, by = local >> 6;
    int k0 = bx * 32, n0 = by * 32;
#pragma unroll
    for (int i = 0; i < 4; ++i)
      t[ty * 4 + i][tx] = o_up[(size_t)(k0 + ty * 4 + i) * 2048 + n0 + tx];
    __syncthreads();
#pragma unroll
    for (int i = 0; i < 4; ++i)
      oupT[(size_t)(n0 + ty * 4 + i) * 2048 + k0 + tx] = f2bf(t[tx][ty * 4 + i]);
  } else {
    int i = (b - 6784) * 256 + tid;
    int s = i >> 4, p = i & 15;
    float inv = powf(10000.f, -(2.f * (float)p) / (float)ROPE_);
    float ang = (float)s * inv;
    rt[i * 2] = cosf(ang);
    rt[i * 2 + 1] = sinf(ang);
  }
}

// ---------------------------------------------------------------------------
// Fused gating softmax + LayerNorm -> kcb/kcbT, reading the c4 K-slice
// PARTIALS directly (sums z=4 slices inline, ascending s -- bit-identical to
// the old reduce_f32 + gate chain). Must run BEFORE q_i reuses the buffer.
// ---------------------------------------------------------------------------
__global__ void gate_ln_kernel(const float* __restrict__ P,
                               const float* __restrict__ ba, const float* __restrict__ bb,
                               const float* __restrict__ w, const float* __restrict__ bias,
                               unsigned short* __restrict__ kcb,
                               unsigned short* __restrict__ kcbT) {
  const size_t n = (size_t)S_ * 256;
  int i = blockIdx.x * 256 + threadIdx.x;
  int j = i >> 6, c = i & 63;
  float lg[8], vv[8];
#pragma unroll
  for (int m = 0; m < 4; ++m) {
    if (j == 0) {
      lg[m] = -1e30f + bb[m * C_ + c];
      vv[m] = 0.f;
    } else {
      size_t idxz = (size_t)((j - 1) * 4 + m) * 256 + 192 + c;
      size_t idxc = (size_t)((j - 1) * 4 + m) * 256 + 64 + c;
      float az = P[idxz], ac = P[idxc];
#pragma unroll
      for (int s = 1; s < 4; ++s) { az += P[s * n + idxz]; ac += P[s * n + idxc]; }
      lg[m] = az + bb[m * C_ + c];
      vv[m] = ac;
    }
    size_t idxz2 = (size_t)(j * 4 + m) * 256 + 128 + c;
    size_t idxc2 = (size_t)(j * 4 + m) * 256 + 0 + c;
    float az2 = P[idxz2], ac2 = P[idxc2];
#pragma unroll
    for (int s = 1; s < 4; ++s) { az2 += P[s * n + idxz2]; ac2 += P[s * n + idxc2]; }
    lg[4 + m] = az2 + ba[m * C_ + c];
    vv[4 + m] = ac2;
  }
  float mx = lg[0];
#pragma unroll
  for (int t = 1; t < 8; ++t) mx = fmaxf(mx, lg[t]);
  float se = 0.f, acc = 0.f;
#pragma unroll
  for (int t = 0; t < 8; ++t) {
    float e = expf(lg[t] - mx);
    se += e;
    acc += e * vv[t];
  }
  float cv = acc / se;
  float mu = wave_sum64(cv) * (1.f / 64.f);
  float d = cv - mu;
  float var = wave_sum64(d * d) * (1.f / 64.f);
  float y = d * (1.f / sqrtf(var + EPS_)) * w[c] + bias[c];
  unsigned short h = f2bf(y);
  kcb[(size_t)j * C_ + c] = h;
  kcbT[(size_t)c * NC_ + j] = h;
}

// LN + RoPE for q -> bf16, pre-scaled by 1/sqrt(C)=0.125 (table-driven trig)
__global__ void ln_rope_q_kernel(const float* __restrict__ quq, const float* __restrict__ w,
                                 const float* __restrict__ b, const float* __restrict__ rt,
                                 unsigned short* __restrict__ qb) {
  int row = blockIdx.x * 4 + (threadIdx.x >> 6);  // s*16 + h
  int s = row >> 4;
  int c = threadIdx.x & 63;
  float v = quq[(size_t)row * C_ + c];
  float mu = wave_sum64(v) * (1.f / 64.f);
  float d = v - mu;
  float var = wave_sum64(d * d) * (1.f / 64.f);
  float y = d * (1.f / sqrtf(var + EPS_)) * w[c] + b[c];
  float outv;
  float partner = __shfl_xor(y, 1, 64);
  if (c < C_ - ROPE_) {
    outv = y;
  } else {
    int p = (c - (C_ - ROPE_)) >> 1;
    float cs = rt[(s * 16 + p) * 2];
    float sn = rt[(s * 16 + p) * 2 + 1];
    if ((c & 1) == 0)
      outv = y * cs - partner * sn;
    else
      outv = partner * sn + y * cs;
  }
  qb[(size_t)row * C_ + c] = f2bf(outv * 0.125f);
}

// ---------------------------------------------------------------------------
// Top-512-of-1024 exact radix-select -> selection bitmap, causal-masked.
// ---------------------------------------------------------------------------
#define MINF_ 0x007FFFFFu
__global__ __launch_bounds__(256) void topk_select_kernel(
    const float* __restrict__ isc, unsigned* __restrict__ sel) {
  __shared__ unsigned mv[NC_];
  __shared__ unsigned bins[256];
  __shared__ unsigned wsum[4];
  __shared__ unsigned sB, sR;
  __shared__ unsigned selw[32];
  int s = blockIdx.x;
  int tid = threadIdx.x;
  int w = tid >> 6, lane = tid & 63;
  if (tid < 32) selw[tid] = 0u;
  for (int i = tid; i < NC_; i += 256) {
    if (i < s) {
      unsigned u = __float_as_uint(isc[(size_t)s * NC_ + i]);
      mv[i] = (u & 0x80000000u) ? ~u : (u | 0x80000000u);
    } else {
      mv[i] = MINF_;
    }
  }
  __syncthreads();
  unsigned K_rem = TOPK_;
  unsigned prefix = 0u;
  for (int lvl = 0; lvl < 4; ++lvl) {
    int shift = 24 - 8 * lvl;
    unsigned pm = (lvl == 0) ? 0u : (0xFFFFFFFFu << (32 - 8 * lvl));
    bins[tid] = 0u;
    __syncthreads();
    for (int i = tid; i < NC_; i += 256) {
      unsigned m = mv[i];
      if ((m & pm) == prefix) atomicAdd(&bins[(m >> shift) & 0xFFu], 1u);
    }
    __syncthreads();
    unsigned v = bins[tid];
    unsigned p = v;
#pragma unroll
    for (int off = 1; off < 64; off <<= 1) {
      unsigned n = __shfl_up(p, (unsigned)off, 64);
      if (lane >= off) p += n;
    }
    if (lane == 63) wsum[w] = p;
    __syncthreads();
    unsigned T = 0, woff = 0;
#pragma unroll
    for (int i = 0; i < 4; ++i) {
      unsigned x_ = wsum[i];
      T += x_;
      if (i < w) woff += x_;
    }
    p += woff;
    unsigned gt = T - p;
    if (gt < K_rem && K_rem <= gt + v) { sB = (unsigned)tid; sR = K_rem - gt; }
    __syncthreads();
    prefix |= (sB << shift);
    K_rem = sR;
  }
  unsigned vstar = prefix;
  unsigned eq = 0;
#pragma unroll
  for (int j = 0; j < 4; ++j) eq += (mv[4 * tid + j] == vstar);
  unsigned rp = eq;
#pragma unroll
  for (int off = 1; off < 64; off <<= 1) {
    unsigned n = __shfl_up(rp, (unsigned)off, 64);
    if (lane >= off) rp += n;
  }
  if (lane == 63) wsum[w] = rp;
  __syncthreads();
  unsigned woff2 = 0;
#pragma unroll
  for (int i = 0; i < 4; ++i)
    if (i < w) woff2 += wsum[i];
  unsigned rank0 = rp + woff2 - eq;
  unsigned local = 0, bits = 0;
#pragma unroll
  for (int j = 0; j < 4; ++j) {
    unsigned m = mv[4 * tid + j];
    int idx = 4 * tid + j;
    bool sb = ((m > vstar) || (m == vstar && (rank0 + local) < K_rem)) && (s < 4 * idx);
    local += (m == vstar);
    if (sb) bits |= (1u << (idx & 31));
  }
  if (bits) atomicOr(&selw[tid >> 3], bits);
  __syncthreads();
  if (tid < 32) sel[(size_t)s * 32 + tid] = selw[tid];
}

// ---------------------------------------------------------------------------
// Dense-masked flash attention, ONE WAVE PER BLOCK, single-pass (no KV split,
// no combine): grid 2048, block = 1 wave = 2 tokens x full causal tile range.
// 2048 tiny blocks (~8/CU resident) average out per-CU tile counts; bf16
// output written directly with denominator division. Barrier-free; stride-68
// p_s (0 conflicts); K/V straight from L2-resident kcb/kcbT.
// ---------------------------------------------------------------------------
#define TS_ 2
__global__ __launch_bounds__(64) void attn_mfma_kernel(
    const unsigned short* __restrict__ qb, const unsigned short* __restrict__ kcb,
    const unsigned short* __restrict__ kcbT, const unsigned* __restrict__ sel,
    const float* __restrict__ sink, unsigned short* __restrict__ out) {
  __shared__ unsigned short p_s[32 * 68];
  __shared__ unsigned selw[TS_][32];
  int tid = threadIdx.x;
  int s0 = blockIdx.x * TS_;
  int lane = tid & 63;
  int qd = lane >> 4, m16 = lane & 15;

  // 64 threads load the 2 tokens' sel rows (wave-private)
  selw[tid >> 5][tid & 31] = sel[(size_t)(s0 + (tid >> 5)) * 32 + (tid & 31)];

  short8 qf[2][2];
#pragma unroll
  for (int tk = 0; tk < 2; ++tk)
#pragma unroll
    for (int ks = 0; ks < 2; ++ks)
      qf[tk][ks] = *(const short8*)&qb[(size_t)(s0 + tk) * 1024 + m16 * 64 + ks * 32 + qd * 8];

  floatx4 of[2][4];
#pragma unroll
  for (int i = 0; i < 2; ++i)
#pragma unroll
    for (int j = 0; j < 4; ++j) of[i][j] = (floatx4){0.f, 0.f, 0.f, 0.f};
  float dsum[2] = {0.f, 0.f};

  int ub = max(511, s0 + TS_ - 2);
  int cs = max(0, (s0 + 4) >> 8);
  int ce = min(16, (ub >> 6) + 1);

  for (int ct = cs; ct < ce; ++ct) {
    int c0 = ct * 64;
#pragma unroll
    for (int mc = 0; mc < 4; ++mc) {
      short8 a0 = *(const short8*)&kcb[(size_t)(c0 + mc * 16 + m16) * 64 + qd * 8];
      short8 a1 = *(const short8*)&kcb[(size_t)(c0 + mc * 16 + m16) * 64 + 32 + qd * 8];
#pragma unroll
      for (int nt = 0; nt < 2; ++nt) {
        floatx4 sc = (floatx4){0.f, 0.f, 0.f, 0.f};
        sc = __builtin_amdgcn_mfma_f32_16x16x32_bf16(a0, qf[nt][0], sc, 0, 0, 0);
        sc = __builtin_amdgcn_mfma_f32_16x16x32_bf16(a1, qf[nt][1], sc, 0, 0, 0);
        unsigned sw = selw[nt][ct * 2 + (mc >> 1)];
        short4v pv;
#pragma unroll
        for (int rg = 0; rg < 4; ++rg) {
          int bitpos = (mc * 16 + qd * 4 + rg) & 31;
          bool ok = ((sw >> bitpos) & 1u) != 0u;
          float e = ok ? __expf(sc[rg]) : 0.f;
          dsum[nt] += e;
          pv[rg] = (short)f2bf(e);
        }
        *(short4v*)&p_s[(nt * 16 + m16) * 68 + mc * 16 + qd * 4] = pv;
      }
    }
#pragma unroll
    for (int ks = 0; ks < 2; ++ks) {
      short8 pa0 = *(const short8*)&p_s[(0 * 16 + m16) * 68 + ks * 32 + qd * 8];
      short8 pa1 = *(const short8*)&p_s[(1 * 16 + m16) * 68 + ks * 32 + qd * 8];
#pragma unroll
      for (int nt = 0; nt < 4; ++nt) {
        short8 bv = *(const short8*)&kcbT[(size_t)(nt * 16 + m16) * NC_ + c0 + ks * 32 + qd * 8];
        of[0][nt] = __builtin_amdgcn_mfma_f32_16x16x32_bf16(pa0, bv, of[0][nt], 0, 0, 0);
        of[1][nt] = __builtin_amdgcn_mfma_f32_16x16x32_bf16(pa1, bv, of[1][nt], 0, 0, 0);
      }
    }
  }
#pragma unroll
  for (int nt = 0; nt < 2; ++nt) {
    dsum[nt] += __shfl_xor(dsum[nt], 16, 64);
    dsum[nt] += __shfl_xor(dsum[nt], 32, 64);
  }
#pragma unroll
  for (int tk = 0; tk < 2; ++tk)
#pragma unroll
    for (int nt = 0; nt < 4; ++nt) {
      floatx4 o = of[tk][nt];
#pragma unroll
      for (int rg = 0; rg < 4; ++rg) {
        int head = qd * 4 + rg;
        float dn = __shfl(dsum[tk], head, 64) + __expf(sink[head]);
        out[(size_t)(s0 + tk) * 1024 + head * 64 + nt * 16 + m16] = f2bf(o[rg] / dn);
      }
    }
}

// ---------------------------------------------------------------------------
// Workspace layout (float offsets)
// ---------------------------------------------------------------------------
#define OFF_QUQ    0u          // quq fp32 / isc / c_q partials
#define OFF_Q      4194304u    // qb bf16
#define OFF_XH     8388608u    // xh bf16
#define OFF_XL     12582912u   // xl bf16 -> sel
#define OFF_PART   16777216u   // k_proj/c4/q_i partials
#define OFF_KO     18874368u   // k_or fp32 (early) -> attnb bf16 (mid)
#define OFF_CQF    22020096u   // qih/qil/kph/kpl overlays
#define OFF_RT     23134208u   // 131072 f : RoPE cos/sin table
#define OFF_WTB    24117248u   // 1048576 f : fused W^T bf16 (2048 x 1024)
#define OFF_CQH    25165824u   // 1048576 f
#define OFF_CQL    26214400u   // 1048576 f
#define OFF_WPACKT 27262976u   // 262144 f
#define OFF_WDQTH  27525120u   // 524288 f
#define OFF_WDQTL  28049408u   // 524288 f
#define OFF_WIUQTH 28573696u   // 65536 f
#define OFF_WIUQTL 28639232u   // 65536 f
#define OFF_WUQT   28704768u   // 262144 f
#define OFF_ODB    28966912u   // 262144 f : o_down bf16
#define OFF_OUPT   29229056u   // 2097152 f
#define OFF_HW     31326208u   // 16384 f
#define OFF_KC     31408128u   // 65536 f : kcb + kcbT
#define OFF_KPR    31473664u   // 65536 f (unused)

extern "C" void kernel_launch(void* const* d_in, const int* in_sizes, int n_in,
                              void* d_out, int out_size, void* d_ws, size_t ws_size,
                              hipStream_t stream) {
  const float* x      = (const float*)d_in[0];
  const float* w_kv_a = (const float*)d_in[1];
  const float* w_kv_b = (const float*)d_in[2];
  const float* w_z_a  = (const float*)d_in[3];
  const float* w_z_b  = (const float*)d_in[4];
  const float* b_a    = (const float*)d_in[5];
  const float* b_b    = (const float*)d_in[6];
  const float* w_dq   = (const float*)d_in[7];
  const float* w_iuq  = (const float*)d_in[8];
  const float* w_w    = (const float*)d_in[9];
  const float* w_k    = (const float*)d_in[10];
  const float* w_uq   = (const float*)d_in[11];
  const float* o_down = (const float*)d_in[12];
  const float* o_up   = (const float*)d_in[13];
  const float* kvn_w  = (const float*)d_in[14];
  const float* kvn_b  = (const float*)d_in[15];
  const float* qn_w   = (const float*)d_in[16];
  const float* qn_b   = (const float*)d_in[17];
  const float* sink   = (const float*)d_in[18];
  float* out = (float*)d_out;
  float* ws = (float*)d_ws;

  float* quq   = ws + OFF_QUQ;
  float* isc   = ws + OFF_QUQ;
  unsigned short* qb = (unsigned short*)(ws + OFF_Q);
  unsigned short* xh = (unsigned short*)(ws + OFF_XH);
  unsigned short* xl = (unsigned short*)(ws + OFF_XL);
  unsigned* sel = (unsigned*)(ws + OFF_XL);
  float* part  = ws + OFF_PART;
  float* k_or  = ws + OFF_KO;
  unsigned short* attnb = (unsigned short*)(ws + OFF_KO);
  unsigned short* qih = (unsigned short*)(ws + OFF_CQF);
  unsigned short* qil = qih + S_ * NHI_ * CI_;
  unsigned short* kph = qil + S_ * NHI_ * CI_;
  unsigned short* kpl = kph + NC_ * CI_;
  float* rt    = ws + OFF_RT;
  unsigned short* wtb = (unsigned short*)(ws + OFF_WTB);
  unsigned short* cqh = (unsigned short*)(ws + OFF_CQH);
  unsigned short* cql = (unsigned short*)(ws + OFF_CQL);
  unsigned short* wpackT = (unsigned short*)(ws + OFF_WPACKT);
  unsigned short* wdqTh  = (unsigned short*)(ws + OFF_WDQTH);
  unsigned short* wdqTl  = (unsigned short*)(ws + OFF_WDQTL);
  unsigned short* wiuqTh = (unsigned short*)(ws + OFF_WIUQTH);
  unsigned short* wiuqTl = (unsigned short*)(ws + OFF_WIUQTL);
  unsigned short* wuqT   = (unsigned short*)(ws + OFF_WUQT);
  unsigned short* odb    = (unsigned short*)(ws + OFF_ODB);
  unsigned short* oupT   = (unsigned short*)(ws + OFF_OUPT);
  float* hw    = ws + OFF_HW;
  unsigned short* kcb  = (unsigned short*)(ws + OFF_KC);
  unsigned short* kcbT = kcb + NC_ * C_;

  dim3 blk(256);

  // --- fused x pass: (hi,lo) split + hw + k_or chunk-mean (one read of x) ---
  cast_split_hw_mean<<<NC_, dim3(512), 0, stream>>>(x, xh, xl, w_w, hw, k_or);
  // --- all weight transposes/casts + rope table in ONE launch ---
  prep_kernel<<<7040, blk, 0, stream>>>(w_kv_a, w_kv_b, w_z_a, w_z_b, wpackT,
                                        w_dq, wdqTh, wdqTl, w_iuq, wiuqTh, wiuqTl,
                                        w_uq, wuqT, o_down, odb, o_up, oupT, rt);

  // --- fused output weight: out = attn @ W (algebraic o_down+o_up fusion) ---
  gemm_bf16_64<<<dim3(2, 32, 4), blk, 0, stream>>>(
      oupT, odb, nullptr, wtb, DG_, D_, DG_, NG_ * 256,
      (long long)DG_, (long long)256 * DG_, 256LL);

  // --- fp32 indexer-side path: k_orig -> k_proj (split-K) + fused cast ---
  gemm_f32_splitk<<<dim3(KSL_, 16), blk, 0, stream>>>(k_or, w_k, part, D_, CI_);
  reduce_splitk_cast<<<256, blk, 0, stream>>>(part, kph, kpl);

  // --- MFMA GEMMs ---
  // c_q: K=2048 -> 4 slices of 512, 128x128 dbuf tile (grid 4x32x4 = 512).
  gemm_bf16_split_128<<<dim3(4, 32, 4), blk, 0, stream>>>(xh, xl, wdqTh, wdqTl, ws,
                                                          512, D_, D_, DC_, 512, 512, (long long)S_ * DC_);
  reduce_cast_split<<<2048, blk, 0, stream>>>(ws, cqh, cql, S_ * DC_, 4);
  // c4: K=2048 -> 4 slices of 512 (grid 2x64x4 = 512 blocks) -> partials
  gemm_bf16_64<<<dim3(2, 64, 4), blk, 0, stream>>>(xh, wpackT, part, nullptr,
                                                   512, D_, D_, 256, 512, 512, (long long)S_ * 256);
  // --- fused gating softmax + LN reads c4 partials directly (before q_i
  //     overwrites the partial buffer) ---
  gate_ln_kernel<<<256, blk, 0, stream>>>(part, b_a, b_b, kvn_w, kvn_b, kcb, kcbT);
  // q_i: K=512 -> 4 slices of 128 (grid 2x64x4 = 512 blocks)
  gemm_bf16_split_64<<<dim3(2, 64, 4), blk, 0, stream>>>(cqh, cql, wiuqTh, wiuqTl, part,
                                                         128, DC_, DC_, 256, 128, 128, (long long)S_ * 256);
  reduce_cast_split<<<1024, blk, 0, stream>>>(part, qih, qil, S_ * 256, 4);
  // quq: grid 8x64 = 512 blocks
  gemm_bf16_64<<<dim3(8, 64, 1), blk, 0, stream>>>(cqh, wuqT, quq, nullptr,
                                                   DC_, DC_, DC_, NH_ * C_, 0, 0, 0);

  // --- q: LN + RoPE (table) -> bf16 scaled by 1/8 ---
  ln_rope_q_kernel<<<16384, blk, 0, stream>>>(quq, qn_w, qn_b, rt, qb);

  // --- indexer scores (split-bf16 MFMA, causal tile skip) + radix-select ---
  iscores_mfma<<<dim3(8, 128), blk, 0, stream>>>(qih, qil, kph, kpl, hw, isc);
  topk_select_kernel<<<S_, blk, 0, stream>>>(isc, sel);

  // --- dense-masked flash attention (1 wave/block, single-pass) ---
  attn_mfma_kernel<<<S_ / TS_, dim3(64), 0, stream>>>(qb, kcb, kcbT, sel, sink, attnb);

  // --- fused output projection: out = attn @ W (128x128 dbuf, XCD-swizzled) ---
  gemm_bf16_128<<<dim3(16, 32, 1), blk, 0, stream>>>(attnb, wtb, out, nullptr,
                                                     NG_ * 256, NH_ * C_, NG_ * 256, D_, 0, 0, 0);
}